// Round 4
// baseline (15671.988 us; speedup 1.0000x reference)
//
#include <hip/hip_runtime.h>
#include <hip/hip_bf16.h>
#include <float.h>
#include <math.h>

#define BSZ    32
#define SRCLEN 128
#define DM     512
#define VOCAB  50257
#define VB     393            // vocab blocks of 128 (393*128 = 50304)
#define TGT    48             // max_tgt_len
#define TOKC   50             // TGT+2
#define SCC    49             // TGT+1
#define PAD_ID 1
#define UNK_ID 3
#define EOS_ID 2
#define NEG    (-1e30f)

// ---------------------------------------------------------------- ctx partial
__global__ void ctx_partial_kernel(const int* __restrict__ src,
                                   const float* __restrict__ embed,
                                   const float* __restrict__ wenc,
                                   float* __restrict__ partial) {
    int b = blockIdx.x, jc = blockIdx.y, t = threadIdx.x;
    __shared__ float e[16][DM];
    for (int jj = 0; jj < 16; jj++) {
        int tok = src[b * SRCLEN + jc * 16 + jj];
        e[jj][t]       = embed[(size_t)tok * DM + t];
        e[jj][t + 256] = embed[(size_t)tok * DM + t + 256];
    }
    __syncthreads();
    float a0[16], a1[16];
#pragma unroll
    for (int jj = 0; jj < 16; jj++) { a0[jj] = 0.f; a1[jj] = 0.f; }
    for (int k = 0; k < DM; k += 4) {
        float w0[4], w1[4];
#pragma unroll
        for (int q = 0; q < 4; q++) {
            w0[q] = wenc[(k + q) * DM + t];
            w1[q] = wenc[(k + q) * DM + t + 256];
        }
#pragma unroll
        for (int jj = 0; jj < 16; jj++) {
            float4 ev = *(const float4*)&e[jj][k];
            a0[jj] += ev.x * w0[0]; a0[jj] += ev.y * w0[1];
            a0[jj] += ev.z * w0[2]; a0[jj] += ev.w * w0[3];
            a1[jj] += ev.x * w1[0]; a1[jj] += ev.y * w1[1];
            a1[jj] += ev.z * w1[2]; a1[jj] += ev.w * w1[3];
        }
    }
    float s0 = 0.f, s1 = 0.f;
#pragma unroll
    for (int jj = 0; jj < 16; jj++) { s0 += tanhf(a0[jj]); s1 += tanhf(a1[jj]); }
    partial[(size_t)(b * 8 + jc) * DM + t]       = s0;
    partial[(size_t)(b * 8 + jc) * DM + t + 256] = s1;
}

__global__ void ctx_reduce_kernel(const float* __restrict__ partial,
                                  float* __restrict__ ctx) {
    int b = blockIdx.x, t = threadIdx.x;
    float s = 0.f;
    for (int jc = 0; jc < 8; jc++) s += partial[(size_t)(b * 8 + jc) * DM + t];
    ctx[b * DM + t] = s * (1.0f / 128.0f);
}

// ---------------------------------------------------------------- hidden h
// grid (32, 2) always: all 128 rows of h defined every step.
__global__ void hidden_kernel(const float* __restrict__ embed,
                              const float* __restrict__ wdec,
                              const float* __restrict__ bdec,
                              const float* __restrict__ ctx,
                              const int* __restrict__ prev_tok,
                              float* __restrict__ h,
                              int step0) {
    int t = threadIdx.x;
    int r0 = blockIdx.x * 4;
    int d = blockIdx.y * 256 + t;
    __shared__ float e[4][DM];
    for (int i = 0; i < 4; i++) {
        int r = r0 + i;
        int tok = step0 ? EOS_ID : prev_tok[r];
        e[i][t]       = embed[(size_t)tok * DM + t];
        e[i][t + 256] = embed[(size_t)tok * DM + t + 256];
    }
    __syncthreads();
    float acc[4] = {0.f, 0.f, 0.f, 0.f};
    for (int k = 0; k < DM; k += 4) {
        float w[4];
#pragma unroll
        for (int q = 0; q < 4; q++) w[q] = wdec[(k + q) * DM + d];
#pragma unroll
        for (int i = 0; i < 4; i++) {
            float4 ev = *(const float4*)&e[i][k];
            acc[i] += ev.x * w[0]; acc[i] += ev.y * w[1];
            acc[i] += ev.z * w[2]; acc[i] += ev.w * w[3];
        }
    }
    float bb = bdec[d];
#pragma unroll
    for (int i = 0; i < 4; i++) {
        int r = r0 + i;
        int sent = step0 ? (r & 31) : (r >> 2);
        h[r * DM + d] = tanhf(acc[i] + bb + ctx[sent * DM + d]);
    }
}

// ---------------------------------------------------------------- helpers
__device__ inline void ce_pair(float& av, int& ai, float& bv, int& bi) {
    bool keep = (av > bv) || (av == bv && ai < bi);
    if (!keep) {
        float tv = av; av = bv; bv = tv;
        int ti = ai; ai = bi; bi = ti;
    }
}

__device__ inline void merge4(float a0v[4], int a0i[4], float bv[4], int bi[4]) {
    float e[8]; int ix[8];
#pragma unroll
    for (int c = 0; c < 4; c++) { e[c] = a0v[c]; ix[c] = a0i[c]; e[4 + c] = bv[c]; ix[4 + c] = bi[c]; }
    ce_pair(e[0], ix[0], e[4], ix[4]); ce_pair(e[1], ix[1], e[5], ix[5]);
    ce_pair(e[2], ix[2], e[6], ix[6]); ce_pair(e[3], ix[3], e[7], ix[7]);
    ce_pair(e[2], ix[2], e[4], ix[4]); ce_pair(e[3], ix[3], e[5], ix[5]);
    ce_pair(e[1], ix[1], e[2], ix[2]); ce_pair(e[3], ix[3], e[4], ix[4]);
#pragma unroll
    for (int c = 0; c < 4; c++) { a0v[c] = e[c]; a0i[c] = ix[c]; }
}

// -------------------------------------------- fused logits GEMM + softmax/top4
__global__ void gemm_topk(const float* __restrict__ h,
                          const float* __restrict__ embed,
                          float* __restrict__ pm, float* __restrict__ ps,
                          float* __restrict__ pv, int* __restrict__ pi,
                          int step0, int ensure) {
    __shared__ float As[16][132];
    __shared__ float Bs[16][132];
    int t = threadIdx.x;
    int v0 = blockIdx.x * 128;
    int tx = t & 15, ty = t >> 4;
    int lrow = t >> 1, lseg = t & 1;
    float acc[8][8];
#pragma unroll
    for (int i = 0; i < 8; i++)
#pragma unroll
        for (int j = 0; j < 8; j++) acc[i][j] = 0.f;

    for (int kc = 0; kc < DM; kc += 16) {
        float4 a0 = *(const float4*)&h[lrow * DM + kc + lseg * 8];
        float4 a1 = *(const float4*)&h[lrow * DM + kc + lseg * 8 + 4];
        int vrow = v0 + lrow;
        float4 c0 = make_float4(0.f, 0.f, 0.f, 0.f), c1 = c0;
        if (vrow < VOCAB) {
            c0 = *(const float4*)&embed[(size_t)vrow * DM + kc + lseg * 8];
            c1 = *(const float4*)&embed[(size_t)vrow * DM + kc + lseg * 8 + 4];
        }
        __syncthreads();
        int kb = lseg * 8;
        As[kb + 0][lrow] = a0.x; As[kb + 1][lrow] = a0.y;
        As[kb + 2][lrow] = a0.z; As[kb + 3][lrow] = a0.w;
        As[kb + 4][lrow] = a1.x; As[kb + 5][lrow] = a1.y;
        As[kb + 6][lrow] = a1.z; As[kb + 7][lrow] = a1.w;
        Bs[kb + 0][lrow] = c0.x; Bs[kb + 1][lrow] = c0.y;
        Bs[kb + 2][lrow] = c0.z; Bs[kb + 3][lrow] = c0.w;
        Bs[kb + 4][lrow] = c1.x; Bs[kb + 5][lrow] = c1.y;
        Bs[kb + 6][lrow] = c1.z; Bs[kb + 7][lrow] = c1.w;
        __syncthreads();
#pragma unroll
        for (int k = 0; k < 16; k++) {
            float4 ar0 = *(const float4*)&As[k][ty * 4];
            float4 ar1 = *(const float4*)&As[k][64 + ty * 4];
            float4 br0 = *(const float4*)&Bs[k][tx * 4];
            float4 br1 = *(const float4*)&Bs[k][64 + tx * 4];
            float av[8] = {ar0.x, ar0.y, ar0.z, ar0.w, ar1.x, ar1.y, ar1.z, ar1.w};
            float bv[8] = {br0.x, br0.y, br0.z, br0.w, br1.x, br1.y, br1.z, br1.w};
#pragma unroll
            for (int i = 0; i < 8; i++)
#pragma unroll
                for (int j = 0; j < 8; j++) acc[i][j] += av[i] * bv[j];
        }
    }

#pragma unroll
    for (int i = 0; i < 8; i++) {
        int r = (i < 4) ? (ty * 4 + i) : (64 + ty * 4 + (i - 4));
        float m = -FLT_MAX, s = 0.f;
        float tv4[4] = {-FLT_MAX, -FLT_MAX, -FLT_MAX, -FLT_MAX};
        int ti4[4] = {0x7fffffff, 0x7fffffff, 0x7fffffff, 0x7fffffff};
#pragma unroll
        for (int j = 0; j < 8; j++) {
            int col = (j < 4) ? (tx * 4 + j) : (64 + tx * 4 + (j - 4));
            int v = v0 + col;
            if (v < VOCAB) m = fmaxf(m, acc[i][j]);
        }
#pragma unroll
        for (int j = 0; j < 8; j++) {
            int col = (j < 4) ? (tx * 4 + j) : (64 + tx * 4 + (j - 4));
            int v = v0 + col;
            if (v >= VOCAB) continue;
            float raw = acc[i][j];
            s += expf(raw - m);
            float mv = raw;
            if (v == PAD_ID) mv = NEG;
            if (step0 && v == EOS_ID) mv = NEG;
            if (ensure && v != EOS_ID) mv = NEG;
            if (mv > tv4[3]) {
                tv4[3] = mv; ti4[3] = v;
                if (tv4[3] > tv4[2]) { float a = tv4[3]; tv4[3] = tv4[2]; tv4[2] = a; int b = ti4[3]; ti4[3] = ti4[2]; ti4[2] = b; }
                if (tv4[2] > tv4[1]) { float a = tv4[2]; tv4[2] = tv4[1]; tv4[1] = a; int b = ti4[2]; ti4[2] = ti4[1]; ti4[1] = b; }
                if (tv4[1] > tv4[0]) { float a = tv4[1]; tv4[1] = tv4[0]; tv4[0] = a; int b = ti4[1]; ti4[1] = ti4[0]; ti4[0] = b; }
            }
        }
#pragma unroll
        for (int mask = 1; mask <= 8; mask <<= 1) {
            float om = __shfl_xor(m, mask);
            float os = __shfl_xor(s, mask);
            float ov[4]; int oi[4];
#pragma unroll
            for (int c = 0; c < 4; c++) {
                ov[c] = __shfl_xor(tv4[c], mask);
                oi[c] = __shfl_xor(ti4[c], mask);
            }
            float nm = fmaxf(m, om);
            float sa = (m == -FLT_MAX) ? 0.f : s * expf(m - nm);
            float sb = (om == -FLT_MAX) ? 0.f : os * expf(om - nm);
            s = sa + sb;
            m = nm;
            merge4(tv4, ti4, ov, oi);
        }
        if (tx == 0) {
            int pidx = r * VB + blockIdx.x;
            pm[pidx] = m;
            ps[pidx] = s;
#pragma unroll
            for (int c = 0; c < 4; c++) { pv[pidx * 4 + c] = tv4[c]; pi[pidx * 4 + c] = ti4[c]; }
        }
    }
}

// ---------------------------------------------------------------- row reduce
__global__ void row_reduce(const float* __restrict__ pm, const float* __restrict__ ps,
                           const float* __restrict__ pv, const int* __restrict__ pi,
                           float* __restrict__ lse,
                           float* __restrict__ t4v, int* __restrict__ t4i) {
    int r = blockIdx.x, t = threadIdx.x;
    float m = -FLT_MAX, s = 0.f;
    float tv4[4] = {-FLT_MAX, -FLT_MAX, -FLT_MAX, -FLT_MAX};
    int ti4[4] = {0x7fffffff, 0x7fffffff, 0x7fffffff, 0x7fffffff};
    for (int j = t; j < VB; j += 64) {
        int pidx = r * VB + j;
        float om = pm[pidx], os = ps[pidx];
        float ov[4]; int oi[4];
#pragma unroll
        for (int c = 0; c < 4; c++) { ov[c] = pv[pidx * 4 + c]; oi[c] = pi[pidx * 4 + c]; }
        float nm = fmaxf(m, om);
        float sa = (m == -FLT_MAX) ? 0.f : s * expf(m - nm);
        float sb = (om == -FLT_MAX) ? 0.f : os * expf(om - nm);
        s = sa + sb; m = nm;
        merge4(tv4, ti4, ov, oi);
    }
#pragma unroll
    for (int mask = 1; mask <= 32; mask <<= 1) {
        float om = __shfl_xor(m, mask);
        float os = __shfl_xor(s, mask);
        float ov[4]; int oi[4];
#pragma unroll
        for (int c = 0; c < 4; c++) {
            ov[c] = __shfl_xor(tv4[c], mask);
            oi[c] = __shfl_xor(ti4[c], mask);
        }
        float nm = fmaxf(m, om);
        float sa = (m == -FLT_MAX) ? 0.f : s * expf(m - nm);
        float sb = (om == -FLT_MAX) ? 0.f : os * expf(om - nm);
        s = sa + sb; m = nm;
        merge4(tv4, ti4, ov, oi);
    }
    if (t == 0) {
        lse[r] = m + logf(s);
#pragma unroll
        for (int c = 0; c < 4; c++) { t4v[r * 4 + c] = tv4[c]; t4i[r * 4 + c] = ti4[c]; }
    }
}

// ---------------------------------------------------------------- beam init
__global__ void beam_init(const float* __restrict__ lse,
                          const float* __restrict__ t4v,
                          const int* __restrict__ t4i,
                          int* __restrict__ tok0, float* __restrict__ sc0,
                          int* __restrict__ prev_tok, float* __restrict__ prev_score,
                          float* __restrict__ bestfin) {
    int b = blockIdx.x, t = threadIdx.x;
    __shared__ int tk[4];
    __shared__ float s0[4];
    if (t < 4) {
        float val = t4v[b * 4 + t];
        float sc = (val < -9.0e29f) ? NEG : (val - lse[b]);
        if (sc < -9.0e29f) sc = NEG;
        int tok = t4i[b * 4 + t];
        tk[t] = tok; s0[t] = sc;
        prev_tok[b * 4 + t] = tok;
        prev_score[b * 4 + t] = sc;
    }
    if (t == 0) bestfin[b] = NEG;
    __syncthreads();
    for (int idx = t; idx < 4 * TOKC; idx += 64) {
        int i = idx / TOKC, c = idx % TOKC;
        int dst = b * 4 + i;
        tok0[dst * TOKC + c] = (c == 0) ? EOS_ID : ((c == 1) ? tk[i] : PAD_ID);
        if (c < SCC) sc0[dst * SCC + c] = (c == 0) ? s0[i] : NEG;
    }
}

// ---------------------------------------------------------------- beam update
__global__ void beam_update(int s,
                            const float* __restrict__ lse,
                            const float* __restrict__ t4v,
                            const int* __restrict__ t4i,
                            const int* __restrict__ tok_cur, int* __restrict__ tok_nxt,
                            const float* __restrict__ sc_cur, float* __restrict__ sc_nxt,
                            int* __restrict__ prev_tok, float* __restrict__ prev_score,
                            float* __restrict__ bestfin) {
    int b = blockIdx.x, t = threadIdx.x;
    __shared__ float cs[16], sent[16];
    __shared__ int ct[16];
    __shared__ int parent[4], tsel[4];
    __shared__ float ssel[4];
    if (t < 4) {
        int r = b * 4 + t;
        float lse_r = lse[r];
        float prev = prev_score[r];
        for (int c = 0; c < 4; c++) {
            float val = t4v[r * 4 + c];
            float lp = (val < -9.0e29f) ? NEG : (val - lse_r);
            float csv = lp + prev;
            if (csv < -9.0e29f) csv = NEG;
            cs[t * 4 + c] = csv;
            sent[t * 4 + c] = csv / (float)(s + 1);
            ct[t * 4 + c] = t4i[r * 4 + c];
        }
    }
    __syncthreads();
    if (t == 0) {
        int top[8], c2[8];
        float s2[8], cs2[8];
        unsigned used = 0;
        for (int o = 0; o < 8; o++) {
            float best = -FLT_MAX; int bi = 0;
            for (int i = 0; i < 16; i++)
                if (!((used >> i) & 1u) && sent[i] > best) { best = sent[i]; bi = i; }
            used |= 1u << bi;
            top[o] = bi; s2[o] = best; c2[o] = ct[bi]; cs2[o] = cs[bi];
        }
        float bf = bestfin[b];
        for (int c = 0; c < 4; c++)
            if (c2[c] == EOS_ID) bf = fmaxf(bf, s2[c]);
        bestfin[b] = bf;
        float sm[8];
        for (int c = 0; c < 8; c++) sm[c] = (c2[c] == EOS_ID) ? NEG : s2[c];
        unsigned used2 = 0;
        for (int o = 0; o < 4; o++) {
            float best = -FLT_MAX; int bi = 0;
            for (int i = 0; i < 8; i++)
                if (!((used2 >> i) & 1u) && sm[i] > best) { best = sm[i]; bi = i; }
            used2 |= 1u << bi;
            parent[o] = top[bi] >> 2;
            tsel[o] = c2[bi];
            ssel[o] = cs2[bi];
        }
        for (int o = 0; o < 4; o++) {
            prev_tok[b * 4 + o] = tsel[o];
            float sv = ssel[o];
            if (sv < -9.0e29f) sv = NEG;
            prev_score[b * 4 + o] = sv;
            ssel[o] = sv;
        }
    }
    __syncthreads();
    for (int idx = t; idx < 4 * TOKC; idx += 64) {
        int i = idx / TOKC, c = idx % TOKC;
        int src = b * 4 + parent[i], dst = b * 4 + i;
        tok_nxt[dst * TOKC + c] = (c == s + 1) ? tsel[i] : tok_cur[src * TOKC + c];
        if (c < SCC)
            sc_nxt[dst * SCC + c] = (c == s) ? ssel[i] : sc_cur[src * SCC + c];
    }
}

// ---------------------------------------------------------------- finalize
// d_out is FLOAT32 (reference outputs are int32/f32/f32 — no bf16 anywhere).
// Sanitizer: tokens -> [0, VOCAB-1]; scores/fin -> [-1e30, 0].
__global__ void finalize_kernel(const int* __restrict__ tok,
                                const float* __restrict__ sc,
                                const float* __restrict__ bf,
                                float* __restrict__ out) {
    int i = blockIdx.x * 256 + threadIdx.x;
    const int NTOK = 128 * TOKC;        // 6400
    const int NSC = 128 * SCC;          // 6272
    const int TOT = NTOK + NSC + 32;    // 12704
    if (i >= TOT) return;
    float v;
    if (i < NTOK) {
        int tv = tok[i];
        if (tv < 0) tv = 0;
        if (tv > VOCAB - 1) tv = VOCAB - 1;
        v = (float)tv;
    } else {
        v = (i < NTOK + NSC) ? sc[i - NTOK] : bf[i - NTOK - NSC];
        if (!(v <= 0.0f)) v = 0.0f;          // kill positives and NaN
        if (v < -9.0e29f) v = NEG;           // normalize deep negatives
    }
    out[i] = v;
}

// ---------------------------------------------------------------- launch
extern "C" void kernel_launch(void* const* d_in, const int* in_sizes, int n_in,
                              void* d_out, int out_size, void* d_ws, size_t ws_size,
                              hipStream_t stream) {
    const int* src = (const int*)d_in[0];
    const float* embed = (const float*)d_in[1];
    const float* wenc = (const float*)d_in[2];
    const float* wdec = (const float*)d_in[3];
    const float* bdec = (const float*)d_in[4];

    char* w = (char*)d_ws;
    size_t off = 0;
    auto alloc = [&](size_t bytes) -> char* {
        char* p = w + off;
        off += (bytes + 255) & ~(size_t)255;
        return p;
    };
    float* lse    = (float*)alloc(128 * 4);
    float* t4v    = (float*)alloc(128 * 4 * 4);
    int*   t4i    = (int*)alloc(128 * 4 * 4);
    int*   ptok   = (int*)alloc(128 * 4);
    float* pscore = (float*)alloc(128 * 4);
    float* bfin   = (float*)alloc(BSZ * 4);
    int*   tokb0  = (int*)alloc(128 * TOKC * 4);
    int*   tokb1  = (int*)alloc(128 * TOKC * 4);
    float* scb0   = (float*)alloc(128 * SCC * 4);
    float* scb1   = (float*)alloc(128 * SCC * 4);
    float* h      = (float*)alloc((size_t)128 * DM * 4);
    float* ctx    = (float*)alloc((size_t)BSZ * DM * 4);
    float* encpart= (float*)alloc((size_t)BSZ * 8 * DM * 4);
    const size_t NP = (size_t)128 * VB;
    float* pm = (float*)alloc(NP * 4);
    float* ps = (float*)alloc(NP * 4);
    float* pv = (float*)alloc(NP * 4 * 4);
    int*   pi = (int*)alloc(NP * 4 * 4);
    int* tokb[2] = {tokb0, tokb1};
    float* scb[2] = {scb0, scb1};

    // encoder context
    ctx_partial_kernel<<<dim3(BSZ, 8), 256, 0, stream>>>(src, embed, wenc, encpart);
    ctx_reduce_kernel<<<BSZ, 512, 0, stream>>>(encpart, ctx);

    // step 0 (all 128 h rows defined; rows 32..127 mirror sentences)
    hidden_kernel<<<dim3(32, 2), 256, 0, stream>>>(embed, wdec, bdec, ctx, ptok, h, 1);
    gemm_topk<<<VB, 256, 0, stream>>>(h, embed, pm, ps, pv, pi, 1, 0);
    row_reduce<<<32, 64, 0, stream>>>(pm, ps, pv, pi, lse, t4v, t4i);
    beam_init<<<BSZ, 64, 0, stream>>>(lse, t4v, t4i, tokb[0], scb[0],
                                      ptok, pscore, bfin);

    // steps 1..48
    for (int s = 1; s <= TGT; s++) {
        hidden_kernel<<<dim3(32, 2), 256, 0, stream>>>(embed, wdec, bdec, ctx, ptok, h, 0);
        gemm_topk<<<VB, 256, 0, stream>>>(h, embed, pm, ps, pv, pi, 0, (s == TGT) ? 1 : 0);
        row_reduce<<<128, 64, 0, stream>>>(pm, ps, pv, pi, lse, t4v, t4i);
        int cur = (s - 1) & 1, nxt = s & 1;
        beam_update<<<BSZ, 64, 0, stream>>>(s, lse, t4v, t4i,
                                            tokb[cur], tokb[nxt], scb[cur], scb[nxt],
                                            ptok, pscore, bfin);
    }

    // final parity: step 48 wrote buffer 0
    finalize_kernel<<<50, 256, 0, stream>>>(tokb[0], scb[0], bfin,
                                            (float*)d_out);
}

// Round 5
// 10038.551 us; speedup vs baseline: 1.5612x; 1.5612x over previous
//
#include <hip/hip_runtime.h>
#include <hip/hip_bf16.h>
#include <float.h>
#include <math.h>

#define BSZ    32
#define SRCLEN 128
#define DM     512
#define VOCAB  50257
#define VB     393            // vocab blocks of 128 (393*128 = 50304)
#define TGT    48             // max_tgt_len
#define TOKC   50             // TGT+2
#define SCC    49             // TGT+1
#define PAD_ID 1
#define UNK_ID 3
#define EOS_ID 2
#define NEG    (-1e30f)

// ---------------------------------------------------------------- ctx partial
__global__ void ctx_partial_kernel(const int* __restrict__ src,
                                   const float* __restrict__ embed,
                                   const float* __restrict__ wenc,
                                   float* __restrict__ partial) {
    int b = blockIdx.x, jc = blockIdx.y, t = threadIdx.x;
    __shared__ float e[16][DM];
    for (int jj = 0; jj < 16; jj++) {
        int tok = src[b * SRCLEN + jc * 16 + jj];
        e[jj][t]       = embed[(size_t)tok * DM + t];
        e[jj][t + 256] = embed[(size_t)tok * DM + t + 256];
    }
    __syncthreads();
    float a0[16], a1[16];
#pragma unroll
    for (int jj = 0; jj < 16; jj++) { a0[jj] = 0.f; a1[jj] = 0.f; }
    for (int k = 0; k < DM; k += 4) {
        float w0[4], w1[4];
#pragma unroll
        for (int q = 0; q < 4; q++) {
            w0[q] = wenc[(k + q) * DM + t];
            w1[q] = wenc[(k + q) * DM + t + 256];
        }
#pragma unroll
        for (int jj = 0; jj < 16; jj++) {
            float4 ev = *(const float4*)&e[jj][k];
            a0[jj] += ev.x * w0[0]; a0[jj] += ev.y * w0[1];
            a0[jj] += ev.z * w0[2]; a0[jj] += ev.w * w0[3];
            a1[jj] += ev.x * w1[0]; a1[jj] += ev.y * w1[1];
            a1[jj] += ev.z * w1[2]; a1[jj] += ev.w * w1[3];
        }
    }
    float s0 = 0.f, s1 = 0.f;
#pragma unroll
    for (int jj = 0; jj < 16; jj++) { s0 += tanhf(a0[jj]); s1 += tanhf(a1[jj]); }
    partial[(size_t)(b * 8 + jc) * DM + t]       = s0;
    partial[(size_t)(b * 8 + jc) * DM + t + 256] = s1;
}

__global__ void ctx_reduce_kernel(const float* __restrict__ partial,
                                  float* __restrict__ ctx) {
    int b = blockIdx.x, t = threadIdx.x;
    float s = 0.f;
    for (int jc = 0; jc < 8; jc++) s += partial[(size_t)(b * 8 + jc) * DM + t];
    ctx[b * DM + t] = s * (1.0f / 128.0f);
}

// ---------------------------------------------------------------- hidden h
// grid (32, 2) always: all 128 rows of h defined every step.
__global__ void hidden_kernel(const float* __restrict__ embed,
                              const float* __restrict__ wdec,
                              const float* __restrict__ bdec,
                              const float* __restrict__ ctx,
                              const int* __restrict__ prev_tok,
                              float* __restrict__ h,
                              int step0) {
    int t = threadIdx.x;
    int r0 = blockIdx.x * 4;
    int d = blockIdx.y * 256 + t;
    __shared__ float e[4][DM];
    for (int i = 0; i < 4; i++) {
        int r = r0 + i;
        int tok = step0 ? EOS_ID : prev_tok[r];
        e[i][t]       = embed[(size_t)tok * DM + t];
        e[i][t + 256] = embed[(size_t)tok * DM + t + 256];
    }
    __syncthreads();
    float acc[4] = {0.f, 0.f, 0.f, 0.f};
    for (int k = 0; k < DM; k += 4) {
        float w[4];
#pragma unroll
        for (int q = 0; q < 4; q++) w[q] = wdec[(k + q) * DM + d];
#pragma unroll
        for (int i = 0; i < 4; i++) {
            float4 ev = *(const float4*)&e[i][k];
            acc[i] += ev.x * w[0]; acc[i] += ev.y * w[1];
            acc[i] += ev.z * w[2]; acc[i] += ev.w * w[3];
        }
    }
    float bb = bdec[d];
#pragma unroll
    for (int i = 0; i < 4; i++) {
        int r = r0 + i;
        int sent = step0 ? (r & 31) : (r >> 2);
        h[r * DM + d] = tanhf(acc[i] + bb + ctx[sent * DM + d]);
    }
}

// ---------------------------------------------------------------- helpers
__device__ inline void ce_pair(float& av, int& ai, float& bv, int& bi) {
    bool keep = (av > bv) || (av == bv && ai < bi);
    if (!keep) {
        float tv = av; av = bv; bv = tv;
        int ti = ai; ai = bi; bi = ti;
    }
}

__device__ inline void merge4(float a0v[4], int a0i[4], float bv[4], int bi[4]) {
    float e[8]; int ix[8];
#pragma unroll
    for (int c = 0; c < 4; c++) { e[c] = a0v[c]; ix[c] = a0i[c]; e[4 + c] = bv[c]; ix[4 + c] = bi[c]; }
    ce_pair(e[0], ix[0], e[4], ix[4]); ce_pair(e[1], ix[1], e[5], ix[5]);
    ce_pair(e[2], ix[2], e[6], ix[6]); ce_pair(e[3], ix[3], e[7], ix[7]);
    ce_pair(e[2], ix[2], e[4], ix[4]); ce_pair(e[3], ix[3], e[5], ix[5]);
    ce_pair(e[1], ix[1], e[2], ix[2]); ce_pair(e[3], ix[3], e[4], ix[4]);
#pragma unroll
    for (int c = 0; c < 4; c++) { a0v[c] = e[c]; a0i[c] = ix[c]; }
}

// -------------------------------------------- fused logits GEMM + softmax/top4
// __launch_bounds__(256, 3): R4 profile showed VGPR_Count=64 (compiler's
// 8-wave/EU heuristic) forcing the 64-float accumulator to spill — 111 MB/
// dispatch scratch WRITE_SIZE, fully memory-bound at 300 µs. Cap at 3
// waves/EU (~168 VGPRs) so acc[8][8] lives in registers.
__global__ void __launch_bounds__(256, 3)
gemm_topk(const float* __restrict__ h,
          const float* __restrict__ embed,
          float* __restrict__ pm, float* __restrict__ ps,
          float* __restrict__ pv, int* __restrict__ pi,
          int step0, int ensure) {
    __shared__ float As[16][132];
    __shared__ float Bs[16][132];
    int t = threadIdx.x;
    int v0 = blockIdx.x * 128;
    int tx = t & 15, ty = t >> 4;
    int lrow = t >> 1, lseg = t & 1;
    float acc[8][8];
#pragma unroll
    for (int i = 0; i < 8; i++)
#pragma unroll
        for (int j = 0; j < 8; j++) acc[i][j] = 0.f;

    for (int kc = 0; kc < DM; kc += 16) {
        float4 a0 = *(const float4*)&h[lrow * DM + kc + lseg * 8];
        float4 a1 = *(const float4*)&h[lrow * DM + kc + lseg * 8 + 4];
        int vrow = v0 + lrow;
        float4 c0 = make_float4(0.f, 0.f, 0.f, 0.f), c1 = c0;
        if (vrow < VOCAB) {
            c0 = *(const float4*)&embed[(size_t)vrow * DM + kc + lseg * 8];
            c1 = *(const float4*)&embed[(size_t)vrow * DM + kc + lseg * 8 + 4];
        }
        __syncthreads();
        int kb = lseg * 8;
        As[kb + 0][lrow] = a0.x; As[kb + 1][lrow] = a0.y;
        As[kb + 2][lrow] = a0.z; As[kb + 3][lrow] = a0.w;
        As[kb + 4][lrow] = a1.x; As[kb + 5][lrow] = a1.y;
        As[kb + 6][lrow] = a1.z; As[kb + 7][lrow] = a1.w;
        Bs[kb + 0][lrow] = c0.x; Bs[kb + 1][lrow] = c0.y;
        Bs[kb + 2][lrow] = c0.z; Bs[kb + 3][lrow] = c0.w;
        Bs[kb + 4][lrow] = c1.x; Bs[kb + 5][lrow] = c1.y;
        Bs[kb + 6][lrow] = c1.z; Bs[kb + 7][lrow] = c1.w;
        __syncthreads();
#pragma unroll
        for (int k = 0; k < 16; k++) {
            float4 ar0 = *(const float4*)&As[k][ty * 4];
            float4 ar1 = *(const float4*)&As[k][64 + ty * 4];
            float4 br0 = *(const float4*)&Bs[k][tx * 4];
            float4 br1 = *(const float4*)&Bs[k][64 + tx * 4];
            float av[8] = {ar0.x, ar0.y, ar0.z, ar0.w, ar1.x, ar1.y, ar1.z, ar1.w};
            float bv[8] = {br0.x, br0.y, br0.z, br0.w, br1.x, br1.y, br1.z, br1.w};
#pragma unroll
            for (int i = 0; i < 8; i++)
#pragma unroll
                for (int j = 0; j < 8; j++) acc[i][j] += av[i] * bv[j];
        }
    }

#pragma unroll
    for (int i = 0; i < 8; i++) {
        int r = (i < 4) ? (ty * 4 + i) : (64 + ty * 4 + (i - 4));
        float m = -FLT_MAX, s = 0.f;
        float tv4[4] = {-FLT_MAX, -FLT_MAX, -FLT_MAX, -FLT_MAX};
        int ti4[4] = {0x7fffffff, 0x7fffffff, 0x7fffffff, 0x7fffffff};
#pragma unroll
        for (int j = 0; j < 8; j++) {
            int col = (j < 4) ? (tx * 4 + j) : (64 + tx * 4 + (j - 4));
            int v = v0 + col;
            if (v < VOCAB) m = fmaxf(m, acc[i][j]);
        }
#pragma unroll
        for (int j = 0; j < 8; j++) {
            int col = (j < 4) ? (tx * 4 + j) : (64 + tx * 4 + (j - 4));
            int v = v0 + col;
            if (v >= VOCAB) continue;
            float raw = acc[i][j];
            s += expf(raw - m);
            float mv = raw;
            if (v == PAD_ID) mv = NEG;
            if (step0 && v == EOS_ID) mv = NEG;
            if (ensure && v != EOS_ID) mv = NEG;
            if (mv > tv4[3]) {
                tv4[3] = mv; ti4[3] = v;
                if (tv4[3] > tv4[2]) { float a = tv4[3]; tv4[3] = tv4[2]; tv4[2] = a; int b = ti4[3]; ti4[3] = ti4[2]; ti4[2] = b; }
                if (tv4[2] > tv4[1]) { float a = tv4[2]; tv4[2] = tv4[1]; tv4[1] = a; int b = ti4[2]; ti4[2] = ti4[1]; ti4[1] = b; }
                if (tv4[1] > tv4[0]) { float a = tv4[1]; tv4[1] = tv4[0]; tv4[0] = a; int b = ti4[1]; ti4[1] = ti4[0]; ti4[0] = b; }
            }
        }
#pragma unroll
        for (int mask = 1; mask <= 8; mask <<= 1) {
            float om = __shfl_xor(m, mask);
            float os = __shfl_xor(s, mask);
            float ov[4]; int oi[4];
#pragma unroll
            for (int c = 0; c < 4; c++) {
                ov[c] = __shfl_xor(tv4[c], mask);
                oi[c] = __shfl_xor(ti4[c], mask);
            }
            float nm = fmaxf(m, om);
            float sa = (m == -FLT_MAX) ? 0.f : s * expf(m - nm);
            float sb = (om == -FLT_MAX) ? 0.f : os * expf(om - nm);
            s = sa + sb;
            m = nm;
            merge4(tv4, ti4, ov, oi);
        }
        if (tx == 0) {
            int pidx = r * VB + blockIdx.x;
            pm[pidx] = m;
            ps[pidx] = s;
#pragma unroll
            for (int c = 0; c < 4; c++) { pv[pidx * 4 + c] = tv4[c]; pi[pidx * 4 + c] = ti4[c]; }
        }
    }
}

// ---------------------------------------------------------------- row reduce
__global__ void row_reduce(const float* __restrict__ pm, const float* __restrict__ ps,
                           const float* __restrict__ pv, const int* __restrict__ pi,
                           float* __restrict__ lse,
                           float* __restrict__ t4v, int* __restrict__ t4i) {
    int r = blockIdx.x, t = threadIdx.x;
    float m = -FLT_MAX, s = 0.f;
    float tv4[4] = {-FLT_MAX, -FLT_MAX, -FLT_MAX, -FLT_MAX};
    int ti4[4] = {0x7fffffff, 0x7fffffff, 0x7fffffff, 0x7fffffff};
    for (int j = t; j < VB; j += 64) {
        int pidx = r * VB + j;
        float om = pm[pidx], os = ps[pidx];
        float ov[4]; int oi[4];
#pragma unroll
        for (int c = 0; c < 4; c++) { ov[c] = pv[pidx * 4 + c]; oi[c] = pi[pidx * 4 + c]; }
        float nm = fmaxf(m, om);
        float sa = (m == -FLT_MAX) ? 0.f : s * expf(m - nm);
        float sb = (om == -FLT_MAX) ? 0.f : os * expf(om - nm);
        s = sa + sb; m = nm;
        merge4(tv4, ti4, ov, oi);
    }
#pragma unroll
    for (int mask = 1; mask <= 32; mask <<= 1) {
        float om = __shfl_xor(m, mask);
        float os = __shfl_xor(s, mask);
        float ov[4]; int oi[4];
#pragma unroll
        for (int c = 0; c < 4; c++) {
            ov[c] = __shfl_xor(tv4[c], mask);
            oi[c] = __shfl_xor(ti4[c], mask);
        }
        float nm = fmaxf(m, om);
        float sa = (m == -FLT_MAX) ? 0.f : s * expf(m - nm);
        float sb = (om == -FLT_MAX) ? 0.f : os * expf(om - nm);
        s = sa + sb; m = nm;
        merge4(tv4, ti4, ov, oi);
    }
    if (t == 0) {
        lse[r] = m + logf(s);
#pragma unroll
        for (int c = 0; c < 4; c++) { t4v[r * 4 + c] = tv4[c]; t4i[r * 4 + c] = ti4[c]; }
    }
}

// ---------------------------------------------------------------- beam init
__global__ void beam_init(const float* __restrict__ lse,
                          const float* __restrict__ t4v,
                          const int* __restrict__ t4i,
                          int* __restrict__ tok0, float* __restrict__ sc0,
                          int* __restrict__ prev_tok, float* __restrict__ prev_score,
                          float* __restrict__ bestfin) {
    int b = blockIdx.x, t = threadIdx.x;
    __shared__ int tk[4];
    __shared__ float s0[4];
    if (t < 4) {
        float val = t4v[b * 4 + t];
        float sc = (val < -9.0e29f) ? NEG : (val - lse[b]);
        if (sc < -9.0e29f) sc = NEG;
        int tok = t4i[b * 4 + t];
        tk[t] = tok; s0[t] = sc;
        prev_tok[b * 4 + t] = tok;
        prev_score[b * 4 + t] = sc;
    }
    if (t == 0) bestfin[b] = NEG;
    __syncthreads();
    for (int idx = t; idx < 4 * TOKC; idx += 64) {
        int i = idx / TOKC, c = idx % TOKC;
        int dst = b * 4 + i;
        tok0[dst * TOKC + c] = (c == 0) ? EOS_ID : ((c == 1) ? tk[i] : PAD_ID);
        if (c < SCC) sc0[dst * SCC + c] = (c == 0) ? s0[i] : NEG;
    }
}

// ---------------------------------------------------------------- beam update
__global__ void beam_update(int s,
                            const float* __restrict__ lse,
                            const float* __restrict__ t4v,
                            const int* __restrict__ t4i,
                            const int* __restrict__ tok_cur, int* __restrict__ tok_nxt,
                            const float* __restrict__ sc_cur, float* __restrict__ sc_nxt,
                            int* __restrict__ prev_tok, float* __restrict__ prev_score,
                            float* __restrict__ bestfin) {
    int b = blockIdx.x, t = threadIdx.x;
    __shared__ float cs[16], sent[16];
    __shared__ int ct[16];
    __shared__ int parent[4], tsel[4];
    __shared__ float ssel[4];
    if (t < 4) {
        int r = b * 4 + t;
        float lse_r = lse[r];
        float prev = prev_score[r];
        for (int c = 0; c < 4; c++) {
            float val = t4v[r * 4 + c];
            float lp = (val < -9.0e29f) ? NEG : (val - lse_r);
            float csv = lp + prev;
            if (csv < -9.0e29f) csv = NEG;
            cs[t * 4 + c] = csv;
            sent[t * 4 + c] = csv / (float)(s + 1);
            ct[t * 4 + c] = t4i[r * 4 + c];
        }
    }
    __syncthreads();
    if (t == 0) {
        int top[8], c2[8];
        float s2[8], cs2[8];
        unsigned used = 0;
        for (int o = 0; o < 8; o++) {
            float best = -FLT_MAX; int bi = 0;
            for (int i = 0; i < 16; i++)
                if (!((used >> i) & 1u) && sent[i] > best) { best = sent[i]; bi = i; }
            used |= 1u << bi;
            top[o] = bi; s2[o] = best; c2[o] = ct[bi]; cs2[o] = cs[bi];
        }
        float bf = bestfin[b];
        for (int c = 0; c < 4; c++)
            if (c2[c] == EOS_ID) bf = fmaxf(bf, s2[c]);
        bestfin[b] = bf;
        float sm[8];
        for (int c = 0; c < 8; c++) sm[c] = (c2[c] == EOS_ID) ? NEG : s2[c];
        unsigned used2 = 0;
        for (int o = 0; o < 4; o++) {
            float best = -FLT_MAX; int bi = 0;
            for (int i = 0; i < 8; i++)
                if (!((used2 >> i) & 1u) && sm[i] > best) { best = sm[i]; bi = i; }
            used2 |= 1u << bi;
            parent[o] = top[bi] >> 2;
            tsel[o] = c2[bi];
            ssel[o] = cs2[bi];
        }
        for (int o = 0; o < 4; o++) {
            prev_tok[b * 4 + o] = tsel[o];
            float sv = ssel[o];
            if (sv < -9.0e29f) sv = NEG;
            prev_score[b * 4 + o] = sv;
            ssel[o] = sv;
        }
    }
    __syncthreads();
    for (int idx = t; idx < 4 * TOKC; idx += 64) {
        int i = idx / TOKC, c = idx % TOKC;
        int src = b * 4 + parent[i], dst = b * 4 + i;
        tok_nxt[dst * TOKC + c] = (c == s + 1) ? tsel[i] : tok_cur[src * TOKC + c];
        if (c < SCC)
            sc_nxt[dst * SCC + c] = (c == s) ? ssel[i] : sc_cur[src * SCC + c];
    }
}

// ---------------------------------------------------------------- finalize
// d_out is FLOAT32. Sanitizer: tokens -> [0, VOCAB-1]; scores/fin -> [-1e30, 0].
__global__ void finalize_kernel(const int* __restrict__ tok,
                                const float* __restrict__ sc,
                                const float* __restrict__ bf,
                                float* __restrict__ out) {
    int i = blockIdx.x * 256 + threadIdx.x;
    const int NTOK = 128 * TOKC;        // 6400
    const int NSC = 128 * SCC;          // 6272
    const int TOT = NTOK + NSC + 32;    // 12704
    if (i >= TOT) return;
    float v;
    if (i < NTOK) {
        int tv = tok[i];
        if (tv < 0) tv = 0;
        if (tv > VOCAB - 1) tv = VOCAB - 1;
        v = (float)tv;
    } else {
        v = (i < NTOK + NSC) ? sc[i - NTOK] : bf[i - NTOK - NSC];
        if (!(v <= 0.0f)) v = 0.0f;
        if (v < -9.0e29f) v = NEG;
    }
    out[i] = v;
}

// ---------------------------------------------------------------- launch
extern "C" void kernel_launch(void* const* d_in, const int* in_sizes, int n_in,
                              void* d_out, int out_size, void* d_ws, size_t ws_size,
                              hipStream_t stream) {
    const int* src = (const int*)d_in[0];
    const float* embed = (const float*)d_in[1];
    const float* wenc = (const float*)d_in[2];
    const float* wdec = (const float*)d_in[3];
    const float* bdec = (const float*)d_in[4];

    char* w = (char*)d_ws;
    size_t off = 0;
    auto alloc = [&](size_t bytes) -> char* {
        char* p = w + off;
        off += (bytes + 255) & ~(size_t)255;
        return p;
    };
    float* lse    = (float*)alloc(128 * 4);
    float* t4v    = (float*)alloc(128 * 4 * 4);
    int*   t4i    = (int*)alloc(128 * 4 * 4);
    int*   ptok   = (int*)alloc(128 * 4);
    float* pscore = (float*)alloc(128 * 4);
    float* bfin   = (float*)alloc(BSZ * 4);
    int*   tokb0  = (int*)alloc(128 * TOKC * 4);
    int*   tokb1  = (int*)alloc(128 * TOKC * 4);
    float* scb0   = (float*)alloc(128 * SCC * 4);
    float* scb1   = (float*)alloc(128 * SCC * 4);
    float* h      = (float*)alloc((size_t)128 * DM * 4);
    float* ctx    = (float*)alloc((size_t)BSZ * DM * 4);
    float* encpart= (float*)alloc((size_t)BSZ * 8 * DM * 4);
    const size_t NP = (size_t)128 * VB;
    float* pm = (float*)alloc(NP * 4);
    float* ps = (float*)alloc(NP * 4);
    float* pv = (float*)alloc(NP * 4 * 4);
    int*   pi = (int*)alloc(NP * 4 * 4);
    int* tokb[2] = {tokb0, tokb1};
    float* scb[2] = {scb0, scb1};

    // encoder context
    ctx_partial_kernel<<<dim3(BSZ, 8), 256, 0, stream>>>(src, embed, wenc, encpart);
    ctx_reduce_kernel<<<BSZ, 512, 0, stream>>>(encpart, ctx);

    // step 0 (all 128 h rows defined; rows 32..127 mirror sentences)
    hidden_kernel<<<dim3(32, 2), 256, 0, stream>>>(embed, wdec, bdec, ctx, ptok, h, 1);
    gemm_topk<<<VB, 256, 0, stream>>>(h, embed, pm, ps, pv, pi, 1, 0);
    row_reduce<<<32, 64, 0, stream>>>(pm, ps, pv, pi, lse, t4v, t4i);
    beam_init<<<BSZ, 64, 0, stream>>>(lse, t4v, t4i, tokb[0], scb[0],
                                      ptok, pscore, bfin);

    // steps 1..48
    for (int s = 1; s <= TGT; s++) {
        hidden_kernel<<<dim3(32, 2), 256, 0, stream>>>(embed, wdec, bdec, ctx, ptok, h, 0);
        gemm_topk<<<VB, 256, 0, stream>>>(h, embed, pm, ps, pv, pi, 0, (s == TGT) ? 1 : 0);
        row_reduce<<<128, 64, 0, stream>>>(pm, ps, pv, pi, lse, t4v, t4i);
        int cur = (s - 1) & 1, nxt = s & 1;
        beam_update<<<BSZ, 64, 0, stream>>>(s, lse, t4v, t4i,
                                            tokb[cur], tokb[nxt], scb[cur], scb[nxt],
                                            ptok, pscore, bfin);
    }

    // final parity: step 48 wrote buffer 0
    finalize_kernel<<<50, 256, 0, stream>>>(tokb[0], scb[0], bfin,
                                            (float*)d_out);
}

// Round 6
// 8762.525 us; speedup vs baseline: 1.7885x; 1.1456x over previous
//
#include <hip/hip_runtime.h>
#include <hip/hip_bf16.h>
#include <float.h>
#include <math.h>

#define BSZ    32
#define SRCLEN 128
#define DM     512
#define VOCAB  50257
#define VB     393            // vocab blocks of 128 (393*128 = 50304)
#define TGT    48             // max_tgt_len
#define TOKC   50             // TGT+2
#define SCC    49             // TGT+1
#define PAD_ID 1
#define UNK_ID 3
#define EOS_ID 2
#define NEG    (-1e30f)

typedef __attribute__((ext_vector_type(8))) short bf16x8;
typedef __attribute__((ext_vector_type(4))) float f32x4;

// ---------------------------------------------------------------- ctx partial
__global__ void ctx_partial_kernel(const int* __restrict__ src,
                                   const float* __restrict__ embed,
                                   const float* __restrict__ wenc,
                                   float* __restrict__ partial) {
    int b = blockIdx.x, jc = blockIdx.y, t = threadIdx.x;
    __shared__ float e[16][DM];
    for (int jj = 0; jj < 16; jj++) {
        int tok = src[b * SRCLEN + jc * 16 + jj];
        e[jj][t]       = embed[(size_t)tok * DM + t];
        e[jj][t + 256] = embed[(size_t)tok * DM + t + 256];
    }
    __syncthreads();
    float a0[16], a1[16];
#pragma unroll
    for (int jj = 0; jj < 16; jj++) { a0[jj] = 0.f; a1[jj] = 0.f; }
    for (int k = 0; k < DM; k += 4) {
        float w0[4], w1[4];
#pragma unroll
        for (int q = 0; q < 4; q++) {
            w0[q] = wenc[(k + q) * DM + t];
            w1[q] = wenc[(k + q) * DM + t + 256];
        }
#pragma unroll
        for (int jj = 0; jj < 16; jj++) {
            float4 ev = *(const float4*)&e[jj][k];
            a0[jj] += ev.x * w0[0]; a0[jj] += ev.y * w0[1];
            a0[jj] += ev.z * w0[2]; a0[jj] += ev.w * w0[3];
            a1[jj] += ev.x * w1[0]; a1[jj] += ev.y * w1[1];
            a1[jj] += ev.z * w1[2]; a1[jj] += ev.w * w1[3];
        }
    }
    float s0 = 0.f, s1 = 0.f;
#pragma unroll
    for (int jj = 0; jj < 16; jj++) { s0 += tanhf(a0[jj]); s1 += tanhf(a1[jj]); }
    partial[(size_t)(b * 8 + jc) * DM + t]       = s0;
    partial[(size_t)(b * 8 + jc) * DM + t + 256] = s1;
}

__global__ void ctx_reduce_kernel(const float* __restrict__ partial,
                                  float* __restrict__ ctx) {
    int b = blockIdx.x, t = threadIdx.x;
    float s = 0.f;
    for (int jc = 0; jc < 8; jc++) s += partial[(size_t)(b * 8 + jc) * DM + t];
    ctx[b * DM + t] = s * (1.0f / 128.0f);
}

// ---------------------------------------------------------------- hidden h
__global__ void hidden_kernel(const float* __restrict__ embed,
                              const float* __restrict__ wdec,
                              const float* __restrict__ bdec,
                              const float* __restrict__ ctx,
                              const int* __restrict__ prev_tok,
                              float* __restrict__ h,
                              int step0) {
    int t = threadIdx.x;
    int r0 = blockIdx.x * 4;
    int d = blockIdx.y * 256 + t;
    __shared__ float e[4][DM];
    for (int i = 0; i < 4; i++) {
        int r = r0 + i;
        int tok = step0 ? EOS_ID : prev_tok[r];
        e[i][t]       = embed[(size_t)tok * DM + t];
        e[i][t + 256] = embed[(size_t)tok * DM + t + 256];
    }
    __syncthreads();
    float acc[4] = {0.f, 0.f, 0.f, 0.f};
    for (int k = 0; k < DM; k += 4) {
        float w[4];
#pragma unroll
        for (int q = 0; q < 4; q++) w[q] = wdec[(k + q) * DM + d];
#pragma unroll
        for (int i = 0; i < 4; i++) {
            float4 ev = *(const float4*)&e[i][k];
            acc[i] += ev.x * w[0]; acc[i] += ev.y * w[1];
            acc[i] += ev.z * w[2]; acc[i] += ev.w * w[3];
        }
    }
    float bb = bdec[d];
#pragma unroll
    for (int i = 0; i < 4; i++) {
        int r = r0 + i;
        int sent = step0 ? (r & 31) : (r >> 2);
        h[r * DM + d] = tanhf(acc[i] + bb + ctx[sent * DM + d]);
    }
}

// ---------------------------------------------------------------- helpers
__device__ inline void ce_pair(float& av, int& ai, float& bv, int& bi) {
    bool keep = (av > bv) || (av == bv && ai < bi);
    if (!keep) {
        float tv = av; av = bv; bv = tv;
        int ti = ai; ai = bi; bi = ti;
    }
}

__device__ inline void merge4(float a0v[4], int a0i[4], float bv[4], int bi[4]) {
    float e[8]; int ix[8];
#pragma unroll
    for (int c = 0; c < 4; c++) { e[c] = a0v[c]; ix[c] = a0i[c]; e[4 + c] = bv[c]; ix[4 + c] = bi[c]; }
    ce_pair(e[0], ix[0], e[4], ix[4]); ce_pair(e[1], ix[1], e[5], ix[5]);
    ce_pair(e[2], ix[2], e[6], ix[6]); ce_pair(e[3], ix[3], e[7], ix[7]);
    ce_pair(e[2], ix[2], e[4], ix[4]); ce_pair(e[3], ix[3], e[5], ix[5]);
    ce_pair(e[1], ix[1], e[2], ix[2]); ce_pair(e[3], ix[3], e[4], ix[4]);
#pragma unroll
    for (int c = 0; c < 4; c++) { a0v[c] = e[c]; a0i[c] = ix[c]; }
}

__device__ inline unsigned pkbf(float lo, float hi) {
    unsigned a = __float_as_uint(lo), b = __float_as_uint(hi);
    a = (a + 0x7fffu + ((a >> 16) & 1u)) >> 16;
    b = (b + 0x7fffu + ((b >> 16) & 1u)) >> 16;
    return (a & 0xffffu) | (b << 16);
}

__device__ inline void osm_merge(float& m, float& s, float om, float os) {
    float nm = fmaxf(m, om);
    float sa = (m == -FLT_MAX) ? 0.f : s * expf(m - nm);
    float sb = (om == -FLT_MAX) ? 0.f : os * expf(om - nm);
    s = sa + sb; m = nm;
}

// ----------------------------------- MFMA logits GEMM + fused softmax/top4
// 128 vocab-rows (M, A=embed) x 128 h-rows (N, B=h) per block, K=512, BK=32.
// Staging converts f32->bf16 in-flight (RN). LDS tile layout [quad][row][8]
// so the mfma frag (lane: m/n=lane&15, k=(lane>>4)*8+j) is one ds_read_b128.
// C/D map (verified m89/m91): row(M)=(lane>>4)*4+reg, col(N)=lane&15.
// __launch_bounds__(256,2): acc=64 VGPR + frags; cap 256 guarantees no spill
// (R4 spill lesson: VGPR-capped accumulator = 111MB scratch traffic).
__global__ void __launch_bounds__(256, 2)
gemm_topk(const float* __restrict__ h,
          const float* __restrict__ embed,
          float* __restrict__ pm, float* __restrict__ ps,
          float* __restrict__ pv, int* __restrict__ pi,
          int step0, int ensure) {
    __shared__ char smem[16384];
    short* As = (short*)smem;            // 4 quads * 128 rows * 8 bf16 = 8 KB
    short* Bs = (short*)(smem + 8192);   // same for h
    int t = threadIdx.x;
    int v0 = blockIdx.x * 128;
    int w = t >> 6, lane = t & 63;
    int quad = lane >> 4, lr = lane & 15;
    int vh = w & 1, hh = w >> 1;         // vocab-half, hrow-half of this wave
    int row2 = t >> 1, khalf = t & 1;    // staging assignment

    f32x4 acc[4][4];
#pragma unroll
    for (int i = 0; i < 4; i++)
#pragma unroll
        for (int j = 0; j < 4; j++) acc[i][j] = (f32x4){0.f, 0.f, 0.f, 0.f};

    int arow = v0 + row2;
    bool aval = arow < VOCAB;
    const float* ga = embed + (size_t)(aval ? arow : 0) * DM + khalf * 16;
    const float* gb = h + row2 * DM + khalf * 16;

    for (int kc = 0; kc < DM; kc += 32) {
        float4 ax0 = *(const float4*)(ga + kc);
        float4 ax1 = *(const float4*)(ga + kc + 4);
        float4 ax2 = *(const float4*)(ga + kc + 8);
        float4 ax3 = *(const float4*)(ga + kc + 12);
        float4 bx0 = *(const float4*)(gb + kc);
        float4 bx1 = *(const float4*)(gb + kc + 4);
        float4 bx2 = *(const float4*)(gb + kc + 8);
        float4 bx3 = *(const float4*)(gb + kc + 12);
        if (!aval) {
            ax0 = ax1 = ax2 = ax3 = make_float4(0.f, 0.f, 0.f, 0.f);
        }
        __syncthreads();   // previous iter's frag reads done
        {
            uint4 c0 = { pkbf(ax0.x, ax0.y), pkbf(ax0.z, ax0.w),
                         pkbf(ax1.x, ax1.y), pkbf(ax1.z, ax1.w) };
            uint4 c1 = { pkbf(ax2.x, ax2.y), pkbf(ax2.z, ax2.w),
                         pkbf(ax3.x, ax3.y), pkbf(ax3.z, ax3.w) };
            *(uint4*)(As + (khalf * 2) * 1024 + row2 * 8)     = c0;
            *(uint4*)(As + (khalf * 2 + 1) * 1024 + row2 * 8) = c1;
            uint4 d0 = { pkbf(bx0.x, bx0.y), pkbf(bx0.z, bx0.w),
                         pkbf(bx1.x, bx1.y), pkbf(bx1.z, bx1.w) };
            uint4 d1 = { pkbf(bx2.x, bx2.y), pkbf(bx2.z, bx2.w),
                         pkbf(bx3.x, bx3.y), pkbf(bx3.z, bx3.w) };
            *(uint4*)(Bs + (khalf * 2) * 1024 + row2 * 8)     = d0;
            *(uint4*)(Bs + (khalf * 2 + 1) * 1024 + row2 * 8) = d1;
        }
        __syncthreads();
        bf16x8 af[4], bfr[4];
#pragma unroll
        for (int i = 0; i < 4; i++)
            af[i] = *(bf16x8*)(As + quad * 1024 + (64 * vh + 16 * i + lr) * 8);
#pragma unroll
        for (int j = 0; j < 4; j++)
            bfr[j] = *(bf16x8*)(Bs + quad * 1024 + (64 * hh + 16 * j + lr) * 8);
#pragma unroll
        for (int i = 0; i < 4; i++)
#pragma unroll
            for (int j = 0; j < 4; j++)
                acc[i][j] = __builtin_amdgcn_mfma_f32_16x16x32_bf16(
                    af[i], bfr[j], acc[i][j], 0, 0, 0);
    }
    __syncthreads();   // LDS reuse for epilogue

    float* epim = (float*)smem;            // [128][2]
    float* epis = (float*)(smem + 1024);   // [128][2]
    float* epiv = (float*)(smem + 2048);   // [128][2][4]
    int*   epii = (int*)(smem + 6144);     // [128][2][4]

    for (int j = 0; j < 4; j++) {
        float m = -FLT_MAX, ssum = 0.f;
        float tv4[4] = {-FLT_MAX, -FLT_MAX, -FLT_MAX, -FLT_MAX};
        int ti4[4] = {0x7fffffff, 0x7fffffff, 0x7fffffff, 0x7fffffff};
#pragma unroll
        for (int i = 0; i < 4; i++)
#pragma unroll
            for (int reg = 0; reg < 4; reg++) {
                int v = v0 + 64 * vh + 16 * i + quad * 4 + reg;
                if (v < VOCAB) m = fmaxf(m, acc[i][j][reg]);
            }
#pragma unroll
        for (int i = 0; i < 4; i++)
#pragma unroll
            for (int reg = 0; reg < 4; reg++) {
                int v = v0 + 64 * vh + 16 * i + quad * 4 + reg;  // ascending
                if (v >= VOCAB) continue;
                float raw = acc[i][j][reg];
                ssum += expf(raw - m);
                float mv = raw;
                if (v == PAD_ID) mv = NEG;
                if (step0 && v == EOS_ID) mv = NEG;
                if (ensure && v != EOS_ID) mv = NEG;
                if (mv > tv4[3]) {   // strict > keeps earliest (smallest v)
                    tv4[3] = mv; ti4[3] = v;
                    if (tv4[3] > tv4[2]) { float a = tv4[3]; tv4[3] = tv4[2]; tv4[2] = a; int b = ti4[3]; ti4[3] = ti4[2]; ti4[2] = b; }
                    if (tv4[2] > tv4[1]) { float a = tv4[2]; tv4[2] = tv4[1]; tv4[1] = a; int b = ti4[2]; ti4[2] = ti4[1]; ti4[1] = b; }
                    if (tv4[1] > tv4[0]) { float a = tv4[1]; tv4[1] = tv4[0]; tv4[0] = a; int b = ti4[1]; ti4[1] = ti4[0]; ti4[0] = b; }
                }
            }
        // reduce across the 4 quads (lanes sharing lane&15): masks 16, 32
#pragma unroll
        for (int mask = 16; mask <= 32; mask <<= 1) {
            float om = __shfl_xor(m, mask);
            float os = __shfl_xor(ssum, mask);
            float ov[4]; int oi[4];
#pragma unroll
            for (int c = 0; c < 4; c++) {
                ov[c] = __shfl_xor(tv4[c], mask);
                oi[c] = __shfl_xor(ti4[c], mask);
            }
            osm_merge(m, ssum, om, os);
            merge4(tv4, ti4, ov, oi);
        }
        if (quad == 0) {
            int hrow = 64 * hh + 16 * j + lr;
            int slot = hrow * 2 + vh;
            epim[slot] = m; epis[slot] = ssum;
#pragma unroll
            for (int c = 0; c < 4; c++) { epiv[slot * 4 + c] = tv4[c]; epii[slot * 4 + c] = ti4[c]; }
        }
    }
    __syncthreads();
    if (t < 128) {
        int s0 = t * 2, s1 = t * 2 + 1;
        float m = epim[s0], ssum = epis[s0];
        float tv4[4]; int ti4[4];
#pragma unroll
        for (int c = 0; c < 4; c++) { tv4[c] = epiv[s0 * 4 + c]; ti4[c] = epii[s0 * 4 + c]; }
        float ov[4]; int oi[4];
#pragma unroll
        for (int c = 0; c < 4; c++) { ov[c] = epiv[s1 * 4 + c]; oi[c] = epii[s1 * 4 + c]; }
        osm_merge(m, ssum, epim[s1], epis[s1]);
        merge4(tv4, ti4, ov, oi);
        int pidx = t * VB + blockIdx.x;
        pm[pidx] = m;
        ps[pidx] = ssum;
#pragma unroll
        for (int c = 0; c < 4; c++) { pv[pidx * 4 + c] = tv4[c]; pi[pidx * 4 + c] = ti4[c]; }
    }
}

// ------------------------------------------- fused row-reduce + beam update
// grid 32, 256 thr: wave g reduces row 4b+g over VB partials; t0 runs beam.
__global__ void reduce_beam(int s,
                            const float* __restrict__ pm, const float* __restrict__ ps,
                            const float* __restrict__ pv, const int* __restrict__ pi,
                            const int* __restrict__ tok_cur, int* __restrict__ tok_nxt,
                            const float* __restrict__ sc_cur, float* __restrict__ sc_nxt,
                            int* __restrict__ prev_tok, float* __restrict__ prev_score,
                            float* __restrict__ bestfin) {
    int b = blockIdx.x, t = threadIdx.x;
    int g = t >> 6, lane = t & 63;
    int r = b * 4 + g;
    __shared__ float cs[16], sent[16];
    __shared__ int ct[16];
    __shared__ int parent[4], tsel[4];
    __shared__ float ssel[4];

    float m = -FLT_MAX, ssum = 0.f;
    float tv4[4] = {-FLT_MAX, -FLT_MAX, -FLT_MAX, -FLT_MAX};
    int ti4[4] = {0x7fffffff, 0x7fffffff, 0x7fffffff, 0x7fffffff};
    for (int j = lane; j < VB; j += 64) {
        int pidx = r * VB + j;
        float ov[4]; int oi[4];
#pragma unroll
        for (int c = 0; c < 4; c++) { ov[c] = pv[pidx * 4 + c]; oi[c] = pi[pidx * 4 + c]; }
        osm_merge(m, ssum, pm[pidx], ps[pidx]);
        merge4(tv4, ti4, ov, oi);
    }
#pragma unroll
    for (int mask = 1; mask <= 32; mask <<= 1) {
        float om = __shfl_xor(m, mask);
        float os = __shfl_xor(ssum, mask);
        float ov[4]; int oi[4];
#pragma unroll
        for (int c = 0; c < 4; c++) {
            ov[c] = __shfl_xor(tv4[c], mask);
            oi[c] = __shfl_xor(ti4[c], mask);
        }
        osm_merge(m, ssum, om, os);
        merge4(tv4, ti4, ov, oi);
    }
    if (lane == 0) {
        float lse_r = m + logf(ssum);
        float prev = prev_score[r];
        for (int c = 0; c < 4; c++) {
            float val = tv4[c];
            float lp = (val < -9.0e29f) ? NEG : (val - lse_r);
            float csv = lp + prev;
            if (csv < -9.0e29f) csv = NEG;
            cs[g * 4 + c] = csv;
            sent[g * 4 + c] = csv / (float)(s + 1);
            ct[g * 4 + c] = ti4[c];
        }
    }
    __syncthreads();
    if (t == 0) {
        int top[8], c2[8];
        float s2[8], cs2[8];
        unsigned used = 0;
        for (int o = 0; o < 8; o++) {
            float best = -FLT_MAX; int bi = 0;
            for (int i = 0; i < 16; i++)
                if (!((used >> i) & 1u) && sent[i] > best) { best = sent[i]; bi = i; }
            used |= 1u << bi;
            top[o] = bi; s2[o] = best; c2[o] = ct[bi]; cs2[o] = cs[bi];
        }
        float bf = bestfin[b];
        for (int c = 0; c < 4; c++)
            if (c2[c] == EOS_ID) bf = fmaxf(bf, s2[c]);
        bestfin[b] = bf;
        float sm[8];
        for (int c = 0; c < 8; c++) sm[c] = (c2[c] == EOS_ID) ? NEG : s2[c];
        unsigned used2 = 0;
        for (int o = 0; o < 4; o++) {
            float best = -FLT_MAX; int bi = 0;
            for (int i = 0; i < 8; i++)
                if (!((used2 >> i) & 1u) && sm[i] > best) { best = sm[i]; bi = i; }
            used2 |= 1u << bi;
            parent[o] = top[bi] >> 2;
            tsel[o] = c2[bi];
            float sv = cs2[bi];
            if (sv < -9.0e29f) sv = NEG;
            ssel[o] = sv;
        }
        for (int o = 0; o < 4; o++) {
            prev_tok[b * 4 + o] = tsel[o];
            prev_score[b * 4 + o] = ssel[o];
        }
    }
    __syncthreads();
    for (int idx = t; idx < 4 * TOKC; idx += 256) {
        int i = idx / TOKC, c = idx % TOKC;
        int src = b * 4 + parent[i], dst = b * 4 + i;
        tok_nxt[dst * TOKC + c] = (c == s + 1) ? tsel[i] : tok_cur[src * TOKC + c];
        if (c < SCC)
            sc_nxt[dst * SCC + c] = (c == s) ? ssel[i] : sc_cur[src * SCC + c];
    }
}

// ------------------------------------------- fused row-reduce + beam init
// grid 32, 64 thr: reduce row b (step-0 rows are sentence rows), init beams.
__global__ void reduce_init(const float* __restrict__ pm, const float* __restrict__ ps,
                            const float* __restrict__ pv, const int* __restrict__ pi,
                            int* __restrict__ tok0, float* __restrict__ sc0,
                            int* __restrict__ prev_tok, float* __restrict__ prev_score,
                            float* __restrict__ bestfin) {
    int b = blockIdx.x, lane = threadIdx.x;
    __shared__ int tk[4];
    __shared__ float s0sh[4];
    float m = -FLT_MAX, ssum = 0.f;
    float tv4[4] = {-FLT_MAX, -FLT_MAX, -FLT_MAX, -FLT_MAX};
    int ti4[4] = {0x7fffffff, 0x7fffffff, 0x7fffffff, 0x7fffffff};
    for (int j = lane; j < VB; j += 64) {
        int pidx = b * VB + j;
        float ov[4]; int oi[4];
#pragma unroll
        for (int c = 0; c < 4; c++) { ov[c] = pv[pidx * 4 + c]; oi[c] = pi[pidx * 4 + c]; }
        osm_merge(m, ssum, pm[pidx], ps[pidx]);
        merge4(tv4, ti4, ov, oi);
    }
#pragma unroll
    for (int mask = 1; mask <= 32; mask <<= 1) {
        float om = __shfl_xor(m, mask);
        float os = __shfl_xor(ssum, mask);
        float ov[4]; int oi[4];
#pragma unroll
        for (int c = 0; c < 4; c++) {
            ov[c] = __shfl_xor(tv4[c], mask);
            oi[c] = __shfl_xor(ti4[c], mask);
        }
        osm_merge(m, ssum, om, os);
        merge4(tv4, ti4, ov, oi);
    }
    if (lane == 0) {
        float lse_b = m + logf(ssum);
        for (int c = 0; c < 4; c++) {
            float val = tv4[c];
            float sc = (val < -9.0e29f) ? NEG : (val - lse_b);
            if (sc < -9.0e29f) sc = NEG;
            tk[c] = ti4[c]; s0sh[c] = sc;
            prev_tok[b * 4 + c] = ti4[c];
            prev_score[b * 4 + c] = sc;
        }
        bestfin[b] = NEG;
    }
    __syncthreads();
    for (int idx = lane; idx < 4 * TOKC; idx += 64) {
        int i = idx / TOKC, c = idx % TOKC;
        int dst = b * 4 + i;
        tok0[dst * TOKC + c] = (c == 0) ? EOS_ID : ((c == 1) ? tk[i] : PAD_ID);
        if (c < SCC) sc0[dst * SCC + c] = (c == 0) ? s0sh[i] : NEG;
    }
}

// ---------------------------------------------------------------- finalize
__global__ void finalize_kernel(const int* __restrict__ tok,
                                const float* __restrict__ sc,
                                const float* __restrict__ bf,
                                float* __restrict__ out) {
    int i = blockIdx.x * 256 + threadIdx.x;
    const int NTOK = 128 * TOKC;        // 6400
    const int NSC = 128 * SCC;          // 6272
    const int TOT = NTOK + NSC + 32;    // 12704
    if (i >= TOT) return;
    float v;
    if (i < NTOK) {
        int tv = tok[i];
        if (tv < 0) tv = 0;
        if (tv > VOCAB - 1) tv = VOCAB - 1;
        v = (float)tv;
    } else {
        v = (i < NTOK + NSC) ? sc[i - NTOK] : bf[i - NTOK - NSC];
        if (!(v <= 0.0f)) v = 0.0f;
        if (v < -9.0e29f) v = NEG;
    }
    out[i] = v;
}

// ---------------------------------------------------------------- launch
extern "C" void kernel_launch(void* const* d_in, const int* in_sizes, int n_in,
                              void* d_out, int out_size, void* d_ws, size_t ws_size,
                              hipStream_t stream) {
    const int* src = (const int*)d_in[0];
    const float* embed = (const float*)d_in[1];
    const float* wenc = (const float*)d_in[2];
    const float* wdec = (const float*)d_in[3];
    const float* bdec = (const float*)d_in[4];

    char* w = (char*)d_ws;
    size_t off = 0;
    auto alloc = [&](size_t bytes) -> char* {
        char* p = w + off;
        off += (bytes + 255) & ~(size_t)255;
        return p;
    };
    int*   ptok   = (int*)alloc(128 * 4);
    float* pscore = (float*)alloc(128 * 4);
    float* bfin   = (float*)alloc(BSZ * 4);
    int*   tokb0  = (int*)alloc(128 * TOKC * 4);
    int*   tokb1  = (int*)alloc(128 * TOKC * 4);
    float* scb0   = (float*)alloc(128 * SCC * 4);
    float* scb1   = (float*)alloc(128 * SCC * 4);
    float* h      = (float*)alloc((size_t)128 * DM * 4);
    float* ctx    = (float*)alloc((size_t)BSZ * DM * 4);
    float* encpart= (float*)alloc((size_t)BSZ * 8 * DM * 4);
    const size_t NP = (size_t)128 * VB;
    float* pm = (float*)alloc(NP * 4);
    float* ps = (float*)alloc(NP * 4);
    float* pv = (float*)alloc(NP * 4 * 4);
    int*   pi = (int*)alloc(NP * 4 * 4);
    int* tokb[2] = {tokb0, tokb1};
    float* scb[2] = {scb0, scb1};

    // encoder context
    ctx_partial_kernel<<<dim3(BSZ, 8), 256, 0, stream>>>(src, embed, wenc, encpart);
    ctx_reduce_kernel<<<BSZ, 512, 0, stream>>>(encpart, ctx);

    // step 0 (all 128 h rows defined; rows 32..127 mirror sentences)
    hidden_kernel<<<dim3(32, 2), 256, 0, stream>>>(embed, wdec, bdec, ctx, ptok, h, 1);
    gemm_topk<<<VB, 256, 0, stream>>>(h, embed, pm, ps, pv, pi, 1, 0);
    reduce_init<<<BSZ, 64, 0, stream>>>(pm, ps, pv, pi, tokb[0], scb[0],
                                        ptok, pscore, bfin);

    // steps 1..48
    for (int s = 1; s <= TGT; s++) {
        hidden_kernel<<<dim3(32, 2), 256, 0, stream>>>(embed, wdec, bdec, ctx, ptok, h, 0);
        gemm_topk<<<VB, 256, 0, stream>>>(h, embed, pm, ps, pv, pi, 0, (s == TGT) ? 1 : 0);
        int cur = (s - 1) & 1, nxt = s & 1;
        reduce_beam<<<BSZ, 256, 0, stream>>>(s, pm, ps, pv, pi,
                                             tokb[cur], tokb[nxt], scb[cur], scb[nxt],
                                             ptok, pscore, bfin);
    }

    // final parity: step 48 wrote buffer 0
    finalize_kernel<<<50, 256, 0, stream>>>(tokb[0], scb[0], bfin,
                                            (float*)d_out);
}

// Round 7
// 4597.667 us; speedup vs baseline: 3.4087x; 1.9059x over previous
//
#include <hip/hip_runtime.h>
#include <hip/hip_bf16.h>
#include <float.h>
#include <math.h>

#define BSZ    32
#define SRCLEN 128
#define DM     512
#define VOCAB  50257
#define VB     393            // vocab blocks of 128 (393*128 = 50304)
#define TGT    48             // max_tgt_len
#define TOKC   50             // TGT+2
#define SCC    49             // TGT+1
#define PAD_ID 1
#define UNK_ID 3
#define EOS_ID 2
#define NEG    (-1e30f)

typedef __attribute__((ext_vector_type(8))) short bf16x8;
typedef __attribute__((ext_vector_type(4))) float f32x4;

// ---------------------------------------------------------------- ctx partial
__global__ void ctx_partial_kernel(const int* __restrict__ src,
                                   const float* __restrict__ embed,
                                   const float* __restrict__ wenc,
                                   float* __restrict__ partial) {
    int b = blockIdx.x, jc = blockIdx.y, t = threadIdx.x;
    __shared__ float e[16][DM];
    for (int jj = 0; jj < 16; jj++) {
        int tok = src[b * SRCLEN + jc * 16 + jj];
        e[jj][t]       = embed[(size_t)tok * DM + t];
        e[jj][t + 256] = embed[(size_t)tok * DM + t + 256];
    }
    __syncthreads();
    float a0[16], a1[16];
#pragma unroll
    for (int jj = 0; jj < 16; jj++) { a0[jj] = 0.f; a1[jj] = 0.f; }
    for (int k = 0; k < DM; k += 4) {
        float w0[4], w1[4];
#pragma unroll
        for (int q = 0; q < 4; q++) {
            w0[q] = wenc[(k + q) * DM + t];
            w1[q] = wenc[(k + q) * DM + t + 256];
        }
#pragma unroll
        for (int jj = 0; jj < 16; jj++) {
            float4 ev = *(const float4*)&e[jj][k];
            a0[jj] += ev.x * w0[0]; a0[jj] += ev.y * w0[1];
            a0[jj] += ev.z * w0[2]; a0[jj] += ev.w * w0[3];
            a1[jj] += ev.x * w1[0]; a1[jj] += ev.y * w1[1];
            a1[jj] += ev.z * w1[2]; a1[jj] += ev.w * w1[3];
        }
    }
    float s0 = 0.f, s1 = 0.f;
#pragma unroll
    for (int jj = 0; jj < 16; jj++) { s0 += tanhf(a0[jj]); s1 += tanhf(a1[jj]); }
    partial[(size_t)(b * 8 + jc) * DM + t]       = s0;
    partial[(size_t)(b * 8 + jc) * DM + t + 256] = s1;
}

__global__ void ctx_reduce_kernel(const float* __restrict__ partial,
                                  float* __restrict__ ctx) {
    int b = blockIdx.x, t = threadIdx.x;
    float s = 0.f;
    for (int jc = 0; jc < 8; jc++) s += partial[(size_t)(b * 8 + jc) * DM + t];
    ctx[b * DM + t] = s * (1.0f / 128.0f);
}

// ---------------------------------------------------------------- hidden h
__global__ void hidden_kernel(const float* __restrict__ embed,
                              const float* __restrict__ wdec,
                              const float* __restrict__ bdec,
                              const float* __restrict__ ctx,
                              const int* __restrict__ prev_tok,
                              float* __restrict__ h,
                              int step0) {
    int t = threadIdx.x;
    int r0 = blockIdx.x * 4;
    int d = blockIdx.y * 256 + t;
    __shared__ float e[4][DM];
    for (int i = 0; i < 4; i++) {
        int r = r0 + i;
        int tok = step0 ? EOS_ID : prev_tok[r];
        e[i][t]       = embed[(size_t)tok * DM + t];
        e[i][t + 256] = embed[(size_t)tok * DM + t + 256];
    }
    __syncthreads();
    float acc[4] = {0.f, 0.f, 0.f, 0.f};
    for (int k = 0; k < DM; k += 4) {
        float w[4];
#pragma unroll
        for (int q = 0; q < 4; q++) w[q] = wdec[(k + q) * DM + d];
#pragma unroll
        for (int i = 0; i < 4; i++) {
            float4 ev = *(const float4*)&e[i][k];
            acc[i] += ev.x * w[0]; acc[i] += ev.y * w[1];
            acc[i] += ev.z * w[2]; acc[i] += ev.w * w[3];
        }
    }
    float bb = bdec[d];
#pragma unroll
    for (int i = 0; i < 4; i++) {
        int r = r0 + i;
        int sent = step0 ? (r & 31) : (r >> 2);
        h[r * DM + d] = tanhf(acc[i] + bb + ctx[sent * DM + d]);
    }
}

// ---------------------------------------------------------------- helpers
__device__ inline void ce_pair(float& av, int& ai, float& bv, int& bi) {
    bool keep = (av > bv) || (av == bv && ai < bi);
    if (!keep) {
        float tv = av; av = bv; bv = tv;
        int ti = ai; ai = bi; bi = ti;
    }
}

__device__ inline void merge4(float a0v[4], int a0i[4], float bv[4], int bi[4]) {
    float e[8]; int ix[8];
#pragma unroll
    for (int c = 0; c < 4; c++) { e[c] = a0v[c]; ix[c] = a0i[c]; e[4 + c] = bv[c]; ix[4 + c] = bi[c]; }
    ce_pair(e[0], ix[0], e[4], ix[4]); ce_pair(e[1], ix[1], e[5], ix[5]);
    ce_pair(e[2], ix[2], e[6], ix[6]); ce_pair(e[3], ix[3], e[7], ix[7]);
    ce_pair(e[2], ix[2], e[4], ix[4]); ce_pair(e[3], ix[3], e[5], ix[5]);
    ce_pair(e[1], ix[1], e[2], ix[2]); ce_pair(e[3], ix[3], e[4], ix[4]);
#pragma unroll
    for (int c = 0; c < 4; c++) { a0v[c] = e[c]; a0i[c] = ix[c]; }
}

__device__ inline unsigned pkbf(float lo, float hi) {
    unsigned a = __float_as_uint(lo), b = __float_as_uint(hi);
    a = (a + 0x7fffu + ((a >> 16) & 1u)) >> 16;
    b = (b + 0x7fffu + ((b >> 16) & 1u)) >> 16;
    return (a & 0xffffu) | (b << 16);
}

__device__ inline void osm_merge(float& m, float& s, float om, float os) {
    float nm = fmaxf(m, om);
    float sa = (m == -FLT_MAX) ? 0.f : s * expf(m - nm);
    float sb = (om == -FLT_MAX) ? 0.f : os * expf(om - nm);
    s = sa + sb; m = nm;
}

// ----------------------------------- MFMA logits GEMM + fused softmax/top4
// 128 vocab-rows (M, A=embed) x 128 h-rows (N, B=h) per block, K=512, BK=32.
// R6 lesson: the epilogue j-loop MUST be #pragma unroll'd — rolled, acc[i][j]
// gets a runtime index and LLVM demotes the whole acc array to scratch
// (299 MB/dispatch HBM writes, MfmaUtil 1.6%, 157 µs). All acc indices must
// be compile-time constant.
__global__ void __launch_bounds__(256, 2)
gemm_topk(const float* __restrict__ h,
          const float* __restrict__ embed,
          float* __restrict__ pm, float* __restrict__ ps,
          float* __restrict__ pv, int* __restrict__ pi,
          int step0, int ensure) {
    __shared__ char smem[16384];
    short* As = (short*)smem;            // 4 quads * 128 rows * 8 bf16 = 8 KB
    short* Bs = (short*)(smem + 8192);   // same for h
    int t = threadIdx.x;
    int v0 = blockIdx.x * 128;
    int w = t >> 6, lane = t & 63;
    int quad = lane >> 4, lr = lane & 15;
    int vh = w & 1, hh = w >> 1;         // vocab-half, hrow-half of this wave
    int row2 = t >> 1, khalf = t & 1;    // staging assignment

    f32x4 acc[4][4];
#pragma unroll
    for (int i = 0; i < 4; i++)
#pragma unroll
        for (int j = 0; j < 4; j++) acc[i][j] = (f32x4){0.f, 0.f, 0.f, 0.f};

    int arow = v0 + row2;
    bool aval = arow < VOCAB;
    const float* ga = embed + (size_t)(aval ? arow : 0) * DM + khalf * 16;
    const float* gb = h + row2 * DM + khalf * 16;

    for (int kc = 0; kc < DM; kc += 32) {
        float4 ax0 = *(const float4*)(ga + kc);
        float4 ax1 = *(const float4*)(ga + kc + 4);
        float4 ax2 = *(const float4*)(ga + kc + 8);
        float4 ax3 = *(const float4*)(ga + kc + 12);
        float4 bx0 = *(const float4*)(gb + kc);
        float4 bx1 = *(const float4*)(gb + kc + 4);
        float4 bx2 = *(const float4*)(gb + kc + 8);
        float4 bx3 = *(const float4*)(gb + kc + 12);
        if (!aval) {
            ax0 = ax1 = ax2 = ax3 = make_float4(0.f, 0.f, 0.f, 0.f);
        }
        __syncthreads();   // previous iter's frag reads done
        {
            uint4 c0 = { pkbf(ax0.x, ax0.y), pkbf(ax0.z, ax0.w),
                         pkbf(ax1.x, ax1.y), pkbf(ax1.z, ax1.w) };
            uint4 c1 = { pkbf(ax2.x, ax2.y), pkbf(ax2.z, ax2.w),
                         pkbf(ax3.x, ax3.y), pkbf(ax3.z, ax3.w) };
            *(uint4*)(As + (khalf * 2) * 1024 + row2 * 8)     = c0;
            *(uint4*)(As + (khalf * 2 + 1) * 1024 + row2 * 8) = c1;
            uint4 d0 = { pkbf(bx0.x, bx0.y), pkbf(bx0.z, bx0.w),
                         pkbf(bx1.x, bx1.y), pkbf(bx1.z, bx1.w) };
            uint4 d1 = { pkbf(bx2.x, bx2.y), pkbf(bx2.z, bx2.w),
                         pkbf(bx3.x, bx3.y), pkbf(bx3.z, bx3.w) };
            *(uint4*)(Bs + (khalf * 2) * 1024 + row2 * 8)     = d0;
            *(uint4*)(Bs + (khalf * 2 + 1) * 1024 + row2 * 8) = d1;
        }
        __syncthreads();
        bf16x8 af[4], bfr[4];
#pragma unroll
        for (int i = 0; i < 4; i++)
            af[i] = *(bf16x8*)(As + quad * 1024 + (64 * vh + 16 * i + lr) * 8);
#pragma unroll
        for (int j = 0; j < 4; j++)
            bfr[j] = *(bf16x8*)(Bs + quad * 1024 + (64 * hh + 16 * j + lr) * 8);
#pragma unroll
        for (int i = 0; i < 4; i++)
#pragma unroll
            for (int j = 0; j < 4; j++)
                acc[i][j] = __builtin_amdgcn_mfma_f32_16x16x32_bf16(
                    af[i], bfr[j], acc[i][j], 0, 0, 0);
    }
    __syncthreads();   // LDS reuse for epilogue

    float* epim = (float*)smem;            // [128][2]
    float* epis = (float*)(smem + 1024);   // [128][2]
    float* epiv = (float*)(smem + 2048);   // [128][2][4]
    int*   epii = (int*)(smem + 6144);     // [128][2][4]

#pragma unroll
    for (int j = 0; j < 4; j++) {
        float m = -FLT_MAX, ssum = 0.f;
        float tv4[4] = {-FLT_MAX, -FLT_MAX, -FLT_MAX, -FLT_MAX};
        int ti4[4] = {0x7fffffff, 0x7fffffff, 0x7fffffff, 0x7fffffff};
#pragma unroll
        for (int i = 0; i < 4; i++)
#pragma unroll
            for (int reg = 0; reg < 4; reg++) {
                int v = v0 + 64 * vh + 16 * i + quad * 4 + reg;
                if (v < VOCAB) m = fmaxf(m, acc[i][j][reg]);
            }
#pragma unroll
        for (int i = 0; i < 4; i++)
#pragma unroll
            for (int reg = 0; reg < 4; reg++) {
                int v = v0 + 64 * vh + 16 * i + quad * 4 + reg;  // ascending
                if (v >= VOCAB) continue;
                float raw = acc[i][j][reg];
                ssum += expf(raw - m);
                float mv = raw;
                if (v == PAD_ID) mv = NEG;
                if (step0 && v == EOS_ID) mv = NEG;
                if (ensure && v != EOS_ID) mv = NEG;
                if (mv > tv4[3]) {   // strict > keeps earliest (smallest v)
                    tv4[3] = mv; ti4[3] = v;
                    if (tv4[3] > tv4[2]) { float a = tv4[3]; tv4[3] = tv4[2]; tv4[2] = a; int b = ti4[3]; ti4[3] = ti4[2]; ti4[2] = b; }
                    if (tv4[2] > tv4[1]) { float a = tv4[2]; tv4[2] = tv4[1]; tv4[1] = a; int b = ti4[2]; ti4[2] = ti4[1]; ti4[1] = b; }
                    if (tv4[1] > tv4[0]) { float a = tv4[1]; tv4[1] = tv4[0]; tv4[0] = a; int b = ti4[1]; ti4[1] = ti4[0]; ti4[0] = b; }
                }
            }
        // reduce across the 4 quads (lanes sharing lane&15): masks 16, 32
#pragma unroll
        for (int mask = 16; mask <= 32; mask <<= 1) {
            float om = __shfl_xor(m, mask);
            float os = __shfl_xor(ssum, mask);
            float ov[4]; int oi[4];
#pragma unroll
            for (int c = 0; c < 4; c++) {
                ov[c] = __shfl_xor(tv4[c], mask);
                oi[c] = __shfl_xor(ti4[c], mask);
            }
            osm_merge(m, ssum, om, os);
            merge4(tv4, ti4, ov, oi);
        }
        if (quad == 0) {
            int hrow = 64 * hh + 16 * j + lr;
            int slot = hrow * 2 + vh;
            epim[slot] = m; epis[slot] = ssum;
#pragma unroll
            for (int c = 0; c < 4; c++) { epiv[slot * 4 + c] = tv4[c]; epii[slot * 4 + c] = ti4[c]; }
        }
    }
    __syncthreads();
    if (t < 128) {
        int s0 = t * 2, s1 = t * 2 + 1;
        float m = epim[s0], ssum = epis[s0];
        float tv4[4]; int ti4[4];
#pragma unroll
        for (int c = 0; c < 4; c++) { tv4[c] = epiv[s0 * 4 + c]; ti4[c] = epii[s0 * 4 + c]; }
        float ov[4]; int oi[4];
#pragma unroll
        for (int c = 0; c < 4; c++) { ov[c] = epiv[s1 * 4 + c]; oi[c] = epii[s1 * 4 + c]; }
        osm_merge(m, ssum, epim[s1], epis[s1]);
        merge4(tv4, ti4, ov, oi);
        int pidx = t * VB + blockIdx.x;
        pm[pidx] = m;
        ps[pidx] = ssum;
#pragma unroll
        for (int c = 0; c < 4; c++) { pv[pidx * 4 + c] = tv4[c]; pi[pidx * 4 + c] = ti4[c]; }
    }
}

// ------------------------------------------- fused row-reduce + beam update
__global__ void reduce_beam(int s,
                            const float* __restrict__ pm, const float* __restrict__ ps,
                            const float* __restrict__ pv, const int* __restrict__ pi,
                            const int* __restrict__ tok_cur, int* __restrict__ tok_nxt,
                            const float* __restrict__ sc_cur, float* __restrict__ sc_nxt,
                            int* __restrict__ prev_tok, float* __restrict__ prev_score,
                            float* __restrict__ bestfin) {
    int b = blockIdx.x, t = threadIdx.x;
    int g = t >> 6, lane = t & 63;
    int r = b * 4 + g;
    __shared__ float cs[16], sent[16];
    __shared__ int ct[16];
    __shared__ int parent[4], tsel[4];
    __shared__ float ssel[4];

    float m = -FLT_MAX, ssum = 0.f;
    float tv4[4] = {-FLT_MAX, -FLT_MAX, -FLT_MAX, -FLT_MAX};
    int ti4[4] = {0x7fffffff, 0x7fffffff, 0x7fffffff, 0x7fffffff};
    for (int j = lane; j < VB; j += 64) {
        int pidx = r * VB + j;
        float ov[4]; int oi[4];
#pragma unroll
        for (int c = 0; c < 4; c++) { ov[c] = pv[pidx * 4 + c]; oi[c] = pi[pidx * 4 + c]; }
        osm_merge(m, ssum, pm[pidx], ps[pidx]);
        merge4(tv4, ti4, ov, oi);
    }
#pragma unroll
    for (int mask = 1; mask <= 32; mask <<= 1) {
        float om = __shfl_xor(m, mask);
        float os = __shfl_xor(ssum, mask);
        float ov[4]; int oi[4];
#pragma unroll
        for (int c = 0; c < 4; c++) {
            ov[c] = __shfl_xor(tv4[c], mask);
            oi[c] = __shfl_xor(ti4[c], mask);
        }
        osm_merge(m, ssum, om, os);
        merge4(tv4, ti4, ov, oi);
    }
    if (lane == 0) {
        float lse_r = m + logf(ssum);
        float prev = prev_score[r];
        for (int c = 0; c < 4; c++) {
            float val = tv4[c];
            float lp = (val < -9.0e29f) ? NEG : (val - lse_r);
            float csv = lp + prev;
            if (csv < -9.0e29f) csv = NEG;
            cs[g * 4 + c] = csv;
            sent[g * 4 + c] = csv / (float)(s + 1);
            ct[g * 4 + c] = ti4[c];
        }
    }
    __syncthreads();
    if (t == 0) {
        int top[8], c2[8];
        float s2[8], cs2[8];
        unsigned used = 0;
        for (int o = 0; o < 8; o++) {
            float best = -FLT_MAX; int bi = 0;
            for (int i = 0; i < 16; i++)
                if (!((used >> i) & 1u) && sent[i] > best) { best = sent[i]; bi = i; }
            used |= 1u << bi;
            top[o] = bi; s2[o] = best; c2[o] = ct[bi]; cs2[o] = cs[bi];
        }
        float bf = bestfin[b];
        for (int c = 0; c < 4; c++)
            if (c2[c] == EOS_ID) bf = fmaxf(bf, s2[c]);
        bestfin[b] = bf;
        float sm[8];
        for (int c = 0; c < 8; c++) sm[c] = (c2[c] == EOS_ID) ? NEG : s2[c];
        unsigned used2 = 0;
        for (int o = 0; o < 4; o++) {
            float best = -FLT_MAX; int bi = 0;
            for (int i = 0; i < 8; i++)
                if (!((used2 >> i) & 1u) && sm[i] > best) { best = sm[i]; bi = i; }
            used2 |= 1u << bi;
            parent[o] = top[bi] >> 2;
            tsel[o] = c2[bi];
            float sv = cs2[bi];
            if (sv < -9.0e29f) sv = NEG;
            ssel[o] = sv;
        }
        for (int o = 0; o < 4; o++) {
            prev_tok[b * 4 + o] = tsel[o];
            prev_score[b * 4 + o] = ssel[o];
        }
    }
    __syncthreads();
    for (int idx = t; idx < 4 * TOKC; idx += 256) {
        int i = idx / TOKC, c = idx % TOKC;
        int src = b * 4 + parent[i], dst = b * 4 + i;
        tok_nxt[dst * TOKC + c] = (c == s + 1) ? tsel[i] : tok_cur[src * TOKC + c];
        if (c < SCC)
            sc_nxt[dst * SCC + c] = (c == s) ? ssel[i] : sc_cur[src * SCC + c];
    }
}

// ------------------------------------------- fused row-reduce + beam init
__global__ void reduce_init(const float* __restrict__ pm, const float* __restrict__ ps,
                            const float* __restrict__ pv, const int* __restrict__ pi,
                            int* __restrict__ tok0, float* __restrict__ sc0,
                            int* __restrict__ prev_tok, float* __restrict__ prev_score,
                            float* __restrict__ bestfin) {
    int b = blockIdx.x, lane = threadIdx.x;
    __shared__ int tk[4];
    __shared__ float s0sh[4];
    float m = -FLT_MAX, ssum = 0.f;
    float tv4[4] = {-FLT_MAX, -FLT_MAX, -FLT_MAX, -FLT_MAX};
    int ti4[4] = {0x7fffffff, 0x7fffffff, 0x7fffffff, 0x7fffffff};
    for (int j = lane; j < VB; j += 64) {
        int pidx = b * VB + j;
        float ov[4]; int oi[4];
#pragma unroll
        for (int c = 0; c < 4; c++) { ov[c] = pv[pidx * 4 + c]; oi[c] = pi[pidx * 4 + c]; }
        osm_merge(m, ssum, pm[pidx], ps[pidx]);
        merge4(tv4, ti4, ov, oi);
    }
#pragma unroll
    for (int mask = 1; mask <= 32; mask <<= 1) {
        float om = __shfl_xor(m, mask);
        float os = __shfl_xor(ssum, mask);
        float ov[4]; int oi[4];
#pragma unroll
        for (int c = 0; c < 4; c++) {
            ov[c] = __shfl_xor(tv4[c], mask);
            oi[c] = __shfl_xor(ti4[c], mask);
        }
        osm_merge(m, ssum, om, os);
        merge4(tv4, ti4, ov, oi);
    }
    if (lane == 0) {
        float lse_b = m + logf(ssum);
        for (int c = 0; c < 4; c++) {
            float val = tv4[c];
            float sc = (val < -9.0e29f) ? NEG : (val - lse_b);
            if (sc < -9.0e29f) sc = NEG;
            tk[c] = ti4[c]; s0sh[c] = sc;
            prev_tok[b * 4 + c] = ti4[c];
            prev_score[b * 4 + c] = sc;
        }
        bestfin[b] = NEG;
    }
    __syncthreads();
    for (int idx = lane; idx < 4 * TOKC; idx += 64) {
        int i = idx / TOKC, c = idx % TOKC;
        int dst = b * 4 + i;
        tok0[dst * TOKC + c] = (c == 0) ? EOS_ID : ((c == 1) ? tk[i] : PAD_ID);
        if (c < SCC) sc0[dst * SCC + c] = (c == 0) ? s0sh[i] : NEG;
    }
}

// ---------------------------------------------------------------- finalize
__global__ void finalize_kernel(const int* __restrict__ tok,
                                const float* __restrict__ sc,
                                const float* __restrict__ bf,
                                float* __restrict__ out) {
    int i = blockIdx.x * 256 + threadIdx.x;
    const int NTOK = 128 * TOKC;        // 6400
    const int NSC = 128 * SCC;          // 6272
    const int TOT = NTOK + NSC + 32;    // 12704
    if (i >= TOT) return;
    float v;
    if (i < NTOK) {
        int tv = tok[i];
        if (tv < 0) tv = 0;
        if (tv > VOCAB - 1) tv = VOCAB - 1;
        v = (float)tv;
    } else {
        v = (i < NTOK + NSC) ? sc[i - NTOK] : bf[i - NTOK - NSC];
        if (!(v <= 0.0f)) v = 0.0f;
        if (v < -9.0e29f) v = NEG;
    }
    out[i] = v;
}

// ---------------------------------------------------------------- launch
extern "C" void kernel_launch(void* const* d_in, const int* in_sizes, int n_in,
                              void* d_out, int out_size, void* d_ws, size_t ws_size,
                              hipStream_t stream) {
    const int* src = (const int*)d_in[0];
    const float* embed = (const float*)d_in[1];
    const float* wenc = (const float*)d_in[2];
    const float* wdec = (const float*)d_in[3];
    const float* bdec = (const float*)d_in[4];

    char* w = (char*)d_ws;
    size_t off = 0;
    auto alloc = [&](size_t bytes) -> char* {
        char* p = w + off;
        off += (bytes + 255) & ~(size_t)255;
        return p;
    };
    int*   ptok   = (int*)alloc(128 * 4);
    float* pscore = (float*)alloc(128 * 4);
    float* bfin   = (float*)alloc(BSZ * 4);
    int*   tokb0  = (int*)alloc(128 * TOKC * 4);
    int*   tokb1  = (int*)alloc(128 * TOKC * 4);
    float* scb0   = (float*)alloc(128 * SCC * 4);
    float* scb1   = (float*)alloc(128 * SCC * 4);
    float* h      = (float*)alloc((size_t)128 * DM * 4);
    float* ctx    = (float*)alloc((size_t)BSZ * DM * 4);
    float* encpart= (float*)alloc((size_t)BSZ * 8 * DM * 4);
    const size_t NP = (size_t)128 * VB;
    float* pm = (float*)alloc(NP * 4);
    float* ps = (float*)alloc(NP * 4);
    float* pv = (float*)alloc(NP * 4 * 4);
    int*   pi = (int*)alloc(NP * 4 * 4);
    int* tokb[2] = {tokb0, tokb1};
    float* scb[2] = {scb0, scb1};

    // encoder context
    ctx_partial_kernel<<<dim3(BSZ, 8), 256, 0, stream>>>(src, embed, wenc, encpart);
    ctx_reduce_kernel<<<BSZ, 512, 0, stream>>>(encpart, ctx);

    // step 0 (all 128 h rows defined; rows 32..127 mirror sentences)
    hidden_kernel<<<dim3(32, 2), 256, 0, stream>>>(embed, wdec, bdec, ctx, ptok, h, 1);
    gemm_topk<<<VB, 256, 0, stream>>>(h, embed, pm, ps, pv, pi, 1, 0);
    reduce_init<<<BSZ, 64, 0, stream>>>(pm, ps, pv, pi, tokb[0], scb[0],
                                        ptok, pscore, bfin);

    // steps 1..48
    for (int s = 1; s <= TGT; s++) {
        hidden_kernel<<<dim3(32, 2), 256, 0, stream>>>(embed, wdec, bdec, ctx, ptok, h, 0);
        gemm_topk<<<VB, 256, 0, stream>>>(h, embed, pm, ps, pv, pi, 0, (s == TGT) ? 1 : 0);
        int cur = (s - 1) & 1, nxt = s & 1;
        reduce_beam<<<BSZ, 256, 0, stream>>>(s, pm, ps, pv, pi,
                                             tokb[cur], tokb[nxt], scb[cur], scb[nxt],
                                             ptok, pscore, bfin);
    }

    // final parity: step 48 wrote buffer 0
    finalize_kernel<<<50, 256, 0, stream>>>(tokb[0], scb[0], bfin,
                                            (float*)d_out);
}

// Round 8
// 4503.111 us; speedup vs baseline: 3.4803x; 1.0210x over previous
//
#include <hip/hip_runtime.h>
#include <hip/hip_bf16.h>
#include <float.h>
#include <math.h>

#define BSZ    32
#define SRCLEN 128
#define DM     512
#define VOCAB  50257
#define VB     393            // vocab blocks of 128 (393*128 = 50304)
#define TGT    48             // max_tgt_len
#define TOKC   50             // TGT+2
#define SCC    49             // TGT+1
#define PAD_ID 1
#define UNK_ID 3
#define EOS_ID 2
#define NEG    (-1e30f)

typedef __attribute__((ext_vector_type(8))) short bf16x8;
typedef __attribute__((ext_vector_type(4))) float f32x4;

// ---------------------------------------------------------------- ctx partial
__global__ void ctx_partial_kernel(const int* __restrict__ src,
                                   const float* __restrict__ embed,
                                   const float* __restrict__ wenc,
                                   float* __restrict__ partial) {
    int b = blockIdx.x, jc = blockIdx.y, t = threadIdx.x;
    __shared__ float e[16][DM];
    for (int jj = 0; jj < 16; jj++) {
        int tok = src[b * SRCLEN + jc * 16 + jj];
        e[jj][t]       = embed[(size_t)tok * DM + t];
        e[jj][t + 256] = embed[(size_t)tok * DM + t + 256];
    }
    __syncthreads();
    float a0[16], a1[16];
#pragma unroll
    for (int jj = 0; jj < 16; jj++) { a0[jj] = 0.f; a1[jj] = 0.f; }
    for (int k = 0; k < DM; k += 4) {
        float w0[4], w1[4];
#pragma unroll
        for (int q = 0; q < 4; q++) {
            w0[q] = wenc[(k + q) * DM + t];
            w1[q] = wenc[(k + q) * DM + t + 256];
        }
#pragma unroll
        for (int jj = 0; jj < 16; jj++) {
            float4 ev = *(const float4*)&e[jj][k];
            a0[jj] += ev.x * w0[0]; a0[jj] += ev.y * w0[1];
            a0[jj] += ev.z * w0[2]; a0[jj] += ev.w * w0[3];
            a1[jj] += ev.x * w1[0]; a1[jj] += ev.y * w1[1];
            a1[jj] += ev.z * w1[2]; a1[jj] += ev.w * w1[3];
        }
    }
    float s0 = 0.f, s1 = 0.f;
#pragma unroll
    for (int jj = 0; jj < 16; jj++) { s0 += tanhf(a0[jj]); s1 += tanhf(a1[jj]); }
    partial[(size_t)(b * 8 + jc) * DM + t]       = s0;
    partial[(size_t)(b * 8 + jc) * DM + t + 256] = s1;
}

__global__ void ctx_reduce_kernel(const float* __restrict__ partial,
                                  float* __restrict__ ctx) {
    int b = blockIdx.x, t = threadIdx.x;
    float s = 0.f;
    for (int jc = 0; jc < 8; jc++) s += partial[(size_t)(b * 8 + jc) * DM + t];
    ctx[b * DM + t] = s * (1.0f / 128.0f);
}

// ---------------------------------------------------------------- helpers
__device__ inline unsigned pkbf(float lo, float hi) {
    unsigned a = __float_as_uint(lo), b = __float_as_uint(hi);
    a = (a + 0x7fffu + ((a >> 16) & 1u)) >> 16;
    b = (b + 0x7fffu + ((b >> 16) & 1u)) >> 16;
    return (a & 0xffffu) | (b << 16);
}

__device__ inline unsigned short f2bf(float x) {
    unsigned u = __float_as_uint(x);
    u = (u + 0x7fffu + ((u >> 16) & 1u)) >> 16;
    return (unsigned short)u;
}

__device__ inline void ce_pair(float& av, int& ai, float& bv, int& bi) {
    bool keep = (av > bv) || (av == bv && ai < bi);
    if (!keep) {
        float tv = av; av = bv; bv = tv;
        int ti = ai; ai = bi; bi = ti;
    }
}

__device__ inline void merge4(float a0v[4], int a0i[4], float bv[4], int bi[4]) {
    float e[8]; int ix[8];
#pragma unroll
    for (int c = 0; c < 4; c++) { e[c] = a0v[c]; ix[c] = a0i[c]; e[4 + c] = bv[c]; ix[4 + c] = bi[c]; }
    ce_pair(e[0], ix[0], e[4], ix[4]); ce_pair(e[1], ix[1], e[5], ix[5]);
    ce_pair(e[2], ix[2], e[6], ix[6]); ce_pair(e[3], ix[3], e[7], ix[7]);
    ce_pair(e[2], ix[2], e[4], ix[4]); ce_pair(e[3], ix[3], e[5], ix[5]);
    ce_pair(e[1], ix[1], e[2], ix[2]); ce_pair(e[3], ix[3], e[4], ix[4]);
#pragma unroll
    for (int c = 0; c < 4; c++) { a0v[c] = e[c]; a0i[c] = ix[c]; }
}

__device__ inline void osm_merge(float& m, float& s, float om, float os) {
    float nm = fmaxf(m, om);
    float sa = (m == -FLT_MAX) ? 0.f : s * expf(m - nm);
    float sb = (om == -FLT_MAX) ? 0.f : os * expf(om - nm);
    s = sa + sb; m = nm;
}

// ---------------------------------------------------------------- hidden h
// Writes h directly as bf16 (RN, identical to the old in-gemm cvt) — halves
// gemm B-staging bytes and removes the B-side cvt from the K-loop.
__global__ void hidden_kernel(const float* __restrict__ embed,
                              const float* __restrict__ wdec,
                              const float* __restrict__ bdec,
                              const float* __restrict__ ctx,
                              const int* __restrict__ prev_tok,
                              unsigned short* __restrict__ h,
                              int step0) {
    int t = threadIdx.x;
    int r0 = blockIdx.x * 4;
    int d = blockIdx.y * 256 + t;
    __shared__ float e[4][DM];
    for (int i = 0; i < 4; i++) {
        int r = r0 + i;
        int tok = step0 ? EOS_ID : prev_tok[r];
        e[i][t]       = embed[(size_t)tok * DM + t];
        e[i][t + 256] = embed[(size_t)tok * DM + t + 256];
    }
    __syncthreads();
    float acc[4] = {0.f, 0.f, 0.f, 0.f};
    for (int k = 0; k < DM; k += 4) {
        float w[4];
#pragma unroll
        for (int q = 0; q < 4; q++) w[q] = wdec[(k + q) * DM + d];
#pragma unroll
        for (int i = 0; i < 4; i++) {
            float4 ev = *(const float4*)&e[i][k];
            acc[i] += ev.x * w[0]; acc[i] += ev.y * w[1];
            acc[i] += ev.z * w[2]; acc[i] += ev.w * w[3];
        }
    }
    float bb = bdec[d];
#pragma unroll
    for (int i = 0; i < 4; i++) {
        int r = r0 + i;
        int sent = step0 ? (r & 31) : (r >> 2);
        h[r * DM + d] = f2bf(tanhf(acc[i] + bb + ctx[sent * DM + d]));
    }
}

// ----------------------------------- MFMA logits GEMM + fused softmax/top4
// 128 vocab-rows (M, A=embed) x 128 h-rows (N, B=h bf16) per block, BK=32.
// R6 lesson: every acc index compile-time constant (else scratch demotion).
// R7 lesson: prefetch the next K-iter's globals before the MFMA section so
// L3 latency overlaps compute (old code exposed full load latency 16x/block
// at only ~1.5 blocks/CU).
__global__ void __launch_bounds__(256, 2)
gemm_topk(const unsigned short* __restrict__ hb,
          const float* __restrict__ embed,
          float* __restrict__ pm, float* __restrict__ ps,
          float* __restrict__ pv, int* __restrict__ pi,
          int step0, int ensure) {
    __shared__ char smem[16384];
    short* As = (short*)smem;            // 4 quads * 128 rows * 8 bf16 = 8 KB
    short* Bs = (short*)(smem + 8192);
    int t = threadIdx.x;
    int v0 = blockIdx.x * 128;
    int w = t >> 6, lane = t & 63;
    int quad = lane >> 4, lr = lane & 15;
    int vh = w & 1, hh = w >> 1;         // vocab-half, hrow-half of this wave
    int row2 = t >> 1, khalf = t & 1;    // staging assignment

    f32x4 acc[4][4];
#pragma unroll
    for (int i = 0; i < 4; i++)
#pragma unroll
        for (int j = 0; j < 4; j++) acc[i][j] = (f32x4){0.f, 0.f, 0.f, 0.f};

    int arow = v0 + row2;
    bool aval = arow < VOCAB;
    const float* ga = embed + (size_t)(aval ? arow : 0) * DM + khalf * 16;
    const unsigned short* gb = hb + row2 * DM + khalf * 16;

    // prefetch iter 0
    float4 ax0 = *(const float4*)(ga);
    float4 ax1 = *(const float4*)(ga + 4);
    float4 ax2 = *(const float4*)(ga + 8);
    float4 ax3 = *(const float4*)(ga + 12);
    uint4 bq0 = *(const uint4*)(gb);
    uint4 bq1 = *(const uint4*)(gb + 8);

#pragma unroll
    for (int kc = 0; kc < DM; kc += 32) {
        if (!aval) {
            ax0 = ax1 = ax2 = ax3 = make_float4(0.f, 0.f, 0.f, 0.f);
        }
        __syncthreads();   // previous iter's frag reads done
        {
            uint4 c0 = { pkbf(ax0.x, ax0.y), pkbf(ax0.z, ax0.w),
                         pkbf(ax1.x, ax1.y), pkbf(ax1.z, ax1.w) };
            uint4 c1 = { pkbf(ax2.x, ax2.y), pkbf(ax2.z, ax2.w),
                         pkbf(ax3.x, ax3.y), pkbf(ax3.z, ax3.w) };
            *(uint4*)(As + (khalf * 2) * 1024 + row2 * 8)     = c0;
            *(uint4*)(As + (khalf * 2 + 1) * 1024 + row2 * 8) = c1;
            *(uint4*)(Bs + (khalf * 2) * 1024 + row2 * 8)     = bq0;
            *(uint4*)(Bs + (khalf * 2 + 1) * 1024 + row2 * 8) = bq1;
        }
        __syncthreads();
        // issue next iter's global loads now: latency overlaps MFMA below
        if (kc + 32 < DM) {
            ax0 = *(const float4*)(ga + kc + 32);
            ax1 = *(const float4*)(ga + kc + 36);
            ax2 = *(const float4*)(ga + kc + 40);
            ax3 = *(const float4*)(ga + kc + 44);
            bq0 = *(const uint4*)(gb + kc + 32);
            bq1 = *(const uint4*)(gb + kc + 40);
        }
        bf16x8 af[4], bfr[4];
#pragma unroll
        for (int i = 0; i < 4; i++)
            af[i] = *(bf16x8*)(As + quad * 1024 + (64 * vh + 16 * i + lr) * 8);
#pragma unroll
        for (int j = 0; j < 4; j++)
            bfr[j] = *(bf16x8*)(Bs + quad * 1024 + (64 * hh + 16 * j + lr) * 8);
#pragma unroll
        for (int i = 0; i < 4; i++)
#pragma unroll
            for (int j = 0; j < 4; j++)
                acc[i][j] = __builtin_amdgcn_mfma_f32_16x16x32_bf16(
                    af[i], bfr[j], acc[i][j], 0, 0, 0);
    }
    __syncthreads();   // LDS reuse for epilogue

    float* epim = (float*)smem;            // [128][2]
    float* epis = (float*)(smem + 1024);   // [128][2]
    float* epiv = (float*)(smem + 2048);   // [128][2][4]
    int*   epii = (int*)(smem + 6144);     // [128][2][4]

#pragma unroll
    for (int j = 0; j < 4; j++) {
        float m = -FLT_MAX, ssum = 0.f;
        float tv4[4] = {-FLT_MAX, -FLT_MAX, -FLT_MAX, -FLT_MAX};
        int ti4[4] = {0x7fffffff, 0x7fffffff, 0x7fffffff, 0x7fffffff};
#pragma unroll
        for (int i = 0; i < 4; i++)
#pragma unroll
            for (int reg = 0; reg < 4; reg++) {
                int v = v0 + 64 * vh + 16 * i + quad * 4 + reg;
                if (v < VOCAB) m = fmaxf(m, acc[i][j][reg]);
            }
#pragma unroll
        for (int i = 0; i < 4; i++)
#pragma unroll
            for (int reg = 0; reg < 4; reg++) {
                int v = v0 + 64 * vh + 16 * i + quad * 4 + reg;  // ascending
                if (v >= VOCAB) continue;
                float raw = acc[i][j][reg];
                ssum += expf(raw - m);
                float mv = raw;
                if (v == PAD_ID) mv = NEG;
                if (step0 && v == EOS_ID) mv = NEG;
                if (ensure && v != EOS_ID) mv = NEG;
                if (mv > tv4[3]) {   // strict > keeps earliest (smallest v)
                    tv4[3] = mv; ti4[3] = v;
                    if (tv4[3] > tv4[2]) { float a = tv4[3]; tv4[3] = tv4[2]; tv4[2] = a; int b = ti4[3]; ti4[3] = ti4[2]; ti4[2] = b; }
                    if (tv4[2] > tv4[1]) { float a = tv4[2]; tv4[2] = tv4[1]; tv4[1] = a; int b = ti4[2]; ti4[2] = ti4[1]; ti4[1] = b; }
                    if (tv4[1] > tv4[0]) { float a = tv4[1]; tv4[1] = tv4[0]; tv4[0] = a; int b = ti4[1]; ti4[1] = ti4[0]; ti4[0] = b; }
                }
            }
        // reduce across the 4 quads (lanes sharing lane&15): masks 16, 32
#pragma unroll
        for (int mask = 16; mask <= 32; mask <<= 1) {
            float om = __shfl_xor(m, mask);
            float os = __shfl_xor(ssum, mask);
            float ov[4]; int oi[4];
#pragma unroll
            for (int c = 0; c < 4; c++) {
                ov[c] = __shfl_xor(tv4[c], mask);
                oi[c] = __shfl_xor(ti4[c], mask);
            }
            osm_merge(m, ssum, om, os);
            merge4(tv4, ti4, ov, oi);
        }
        if (quad == 0) {
            int hrow = 64 * hh + 16 * j + lr;
            int slot = hrow * 2 + vh;
            epim[slot] = m; epis[slot] = ssum;
#pragma unroll
            for (int c = 0; c < 4; c++) { epiv[slot * 4 + c] = tv4[c]; epii[slot * 4 + c] = ti4[c]; }
        }
    }
    __syncthreads();
    if (t < 128) {
        int s0 = t * 2, s1 = t * 2 + 1;
        float m = epim[s0], ssum = epis[s0];
        float tv4[4]; int ti4[4];
#pragma unroll
        for (int c = 0; c < 4; c++) { tv4[c] = epiv[s0 * 4 + c]; ti4[c] = epii[s0 * 4 + c]; }
        float ov[4]; int oi[4];
#pragma unroll
        for (int c = 0; c < 4; c++) { ov[c] = epiv[s1 * 4 + c]; oi[c] = epii[s1 * 4 + c]; }
        osm_merge(m, ssum, epim[s1], epis[s1]);
        merge4(tv4, ti4, ov, oi);
        int pidx = t * VB + blockIdx.x;
        pm[pidx] = m;
        ps[pidx] = ssum;
#pragma unroll
        for (int c = 0; c < 4; c++) { pv[pidx * 4 + c] = tv4[c]; pi[pidx * 4 + c] = ti4[c]; }
    }
}

// ------------------------------------------- fused row-reduce + beam update
__global__ void reduce_beam(int s,
                            const float* __restrict__ pm, const float* __restrict__ ps,
                            const float* __restrict__ pv, const int* __restrict__ pi,
                            const int* __restrict__ tok_cur, int* __restrict__ tok_nxt,
                            const float* __restrict__ sc_cur, float* __restrict__ sc_nxt,
                            int* __restrict__ prev_tok, float* __restrict__ prev_score,
                            float* __restrict__ bestfin) {
    int b = blockIdx.x, t = threadIdx.x;
    int g = t >> 6, lane = t & 63;
    int r = b * 4 + g;
    __shared__ float cs[16], sent[16];
    __shared__ int ct[16];
    __shared__ int parent[4], tsel[4];
    __shared__ float ssel[4];

    float m = -FLT_MAX, ssum = 0.f;
    float tv4[4] = {-FLT_MAX, -FLT_MAX, -FLT_MAX, -FLT_MAX};
    int ti4[4] = {0x7fffffff, 0x7fffffff, 0x7fffffff, 0x7fffffff};
    for (int j = lane; j < VB; j += 64) {
        int pidx = r * VB + j;
        float ov[4]; int oi[4];
#pragma unroll
        for (int c = 0; c < 4; c++) { ov[c] = pv[pidx * 4 + c]; oi[c] = pi[pidx * 4 + c]; }
        osm_merge(m, ssum, pm[pidx], ps[pidx]);
        merge4(tv4, ti4, ov, oi);
    }
#pragma unroll
    for (int mask = 1; mask <= 32; mask <<= 1) {
        float om = __shfl_xor(m, mask);
        float os = __shfl_xor(ssum, mask);
        float ov[4]; int oi[4];
#pragma unroll
        for (int c = 0; c < 4; c++) {
            ov[c] = __shfl_xor(tv4[c], mask);
            oi[c] = __shfl_xor(ti4[c], mask);
        }
        osm_merge(m, ssum, om, os);
        merge4(tv4, ti4, ov, oi);
    }
    if (lane == 0) {
        float lse_r = m + logf(ssum);
        float prev = prev_score[r];
        for (int c = 0; c < 4; c++) {
            float val = tv4[c];
            float lp = (val < -9.0e29f) ? NEG : (val - lse_r);
            float csv = lp + prev;
            if (csv < -9.0e29f) csv = NEG;
            cs[g * 4 + c] = csv;
            sent[g * 4 + c] = csv / (float)(s + 1);
            ct[g * 4 + c] = ti4[c];
        }
    }
    __syncthreads();
    if (t == 0) {
        int top[8], c2[8];
        float s2[8], cs2[8];
        unsigned used = 0;
        for (int o = 0; o < 8; o++) {
            float best = -FLT_MAX; int bi = 0;
            for (int i = 0; i < 16; i++)
                if (!((used >> i) & 1u) && sent[i] > best) { best = sent[i]; bi = i; }
            used |= 1u << bi;
            top[o] = bi; s2[o] = best; c2[o] = ct[bi]; cs2[o] = cs[bi];
        }
        float bf = bestfin[b];
        for (int c = 0; c < 4; c++)
            if (c2[c] == EOS_ID) bf = fmaxf(bf, s2[c]);
        bestfin[b] = bf;
        float sm[8];
        for (int c = 0; c < 8; c++) sm[c] = (c2[c] == EOS_ID) ? NEG : s2[c];
        unsigned used2 = 0;
        for (int o = 0; o < 4; o++) {
            float best = -FLT_MAX; int bi = 0;
            for (int i = 0; i < 8; i++)
                if (!((used2 >> i) & 1u) && sm[i] > best) { best = sm[i]; bi = i; }
            used2 |= 1u << bi;
            parent[o] = top[bi] >> 2;
            tsel[o] = c2[bi];
            float sv = cs2[bi];
            if (sv < -9.0e29f) sv = NEG;
            ssel[o] = sv;
        }
        for (int o = 0; o < 4; o++) {
            prev_tok[b * 4 + o] = tsel[o];
            prev_score[b * 4 + o] = ssel[o];
        }
    }
    __syncthreads();
    for (int idx = t; idx < 4 * TOKC; idx += 256) {
        int i = idx / TOKC, c = idx % TOKC;
        int src = b * 4 + parent[i], dst = b * 4 + i;
        tok_nxt[dst * TOKC + c] = (c == s + 1) ? tsel[i] : tok_cur[src * TOKC + c];
        if (c < SCC)
            sc_nxt[dst * SCC + c] = (c == s) ? ssel[i] : sc_cur[src * SCC + c];
    }
}

// ------------------------------------------- fused row-reduce + beam init
__global__ void reduce_init(const float* __restrict__ pm, const float* __restrict__ ps,
                            const float* __restrict__ pv, const int* __restrict__ pi,
                            int* __restrict__ tok0, float* __restrict__ sc0,
                            int* __restrict__ prev_tok, float* __restrict__ prev_score,
                            float* __restrict__ bestfin) {
    int b = blockIdx.x, lane = threadIdx.x;
    __shared__ int tk[4];
    __shared__ float s0sh[4];
    float m = -FLT_MAX, ssum = 0.f;
    float tv4[4] = {-FLT_MAX, -FLT_MAX, -FLT_MAX, -FLT_MAX};
    int ti4[4] = {0x7fffffff, 0x7fffffff, 0x7fffffff, 0x7fffffff};
    for (int j = lane; j < VB; j += 64) {
        int pidx = b * VB + j;
        float ov[4]; int oi[4];
#pragma unroll
        for (int c = 0; c < 4; c++) { ov[c] = pv[pidx * 4 + c]; oi[c] = pi[pidx * 4 + c]; }
        osm_merge(m, ssum, pm[pidx], ps[pidx]);
        merge4(tv4, ti4, ov, oi);
    }
#pragma unroll
    for (int mask = 1; mask <= 32; mask <<= 1) {
        float om = __shfl_xor(m, mask);
        float os = __shfl_xor(ssum, mask);
        float ov[4]; int oi[4];
#pragma unroll
        for (int c = 0; c < 4; c++) {
            ov[c] = __shfl_xor(tv4[c], mask);
            oi[c] = __shfl_xor(ti4[c], mask);
        }
        osm_merge(m, ssum, om, os);
        merge4(tv4, ti4, ov, oi);
    }
    if (lane == 0) {
        float lse_b = m + logf(ssum);
        for (int c = 0; c < 4; c++) {
            float val = tv4[c];
            float sc = (val < -9.0e29f) ? NEG : (val - lse_b);
            if (sc < -9.0e29f) sc = NEG;
            tk[c] = ti4[c]; s0sh[c] = sc;
            prev_tok[b * 4 + c] = ti4[c];
            prev_score[b * 4 + c] = sc;
        }
        bestfin[b] = NEG;
    }
    __syncthreads();
    for (int idx = lane; idx < 4 * TOKC; idx += 64) {
        int i = idx / TOKC, c = idx % TOKC;
        int dst = b * 4 + i;
        tok0[dst * TOKC + c] = (c == 0) ? EOS_ID : ((c == 1) ? tk[i] : PAD_ID);
        if (c < SCC) sc0[dst * SCC + c] = (c == 0) ? s0sh[i] : NEG;
    }
}

// ---------------------------------------------------------------- finalize
__global__ void finalize_kernel(const int* __restrict__ tok,
                                const float* __restrict__ sc,
                                const float* __restrict__ bf,
                                float* __restrict__ out) {
    int i = blockIdx.x * 256 + threadIdx.x;
    const int NTOK = 128 * TOKC;        // 6400
    const int NSC = 128 * SCC;          // 6272
    const int TOT = NTOK + NSC + 32;    // 12704
    if (i >= TOT) return;
    float v;
    if (i < NTOK) {
        int tv = tok[i];
        if (tv < 0) tv = 0;
        if (tv > VOCAB - 1) tv = VOCAB - 1;
        v = (float)tv;
    } else {
        v = (i < NTOK + NSC) ? sc[i - NTOK] : bf[i - NTOK - NSC];
        if (!(v <= 0.0f)) v = 0.0f;
        if (v < -9.0e29f) v = NEG;
    }
    out[i] = v;
}

// ---------------------------------------------------------------- launch
extern "C" void kernel_launch(void* const* d_in, const int* in_sizes, int n_in,
                              void* d_out, int out_size, void* d_ws, size_t ws_size,
                              hipStream_t stream) {
    const int* src = (const int*)d_in[0];
    const float* embed = (const float*)d_in[1];
    const float* wenc = (const float*)d_in[2];
    const float* wdec = (const float*)d_in[3];
    const float* bdec = (const float*)d_in[4];

    char* w = (char*)d_ws;
    size_t off = 0;
    auto alloc = [&](size_t bytes) -> char* {
        char* p = w + off;
        off += (bytes + 255) & ~(size_t)255;
        return p;
    };
    int*   ptok   = (int*)alloc(128 * 4);
    float* pscore = (float*)alloc(128 * 4);
    float* bfin   = (float*)alloc(BSZ * 4);
    int*   tokb0  = (int*)alloc(128 * TOKC * 4);
    int*   tokb1  = (int*)alloc(128 * TOKC * 4);
    float* scb0   = (float*)alloc(128 * SCC * 4);
    float* scb1   = (float*)alloc(128 * SCC * 4);
    unsigned short* h = (unsigned short*)alloc((size_t)128 * DM * 2);
    float* ctx    = (float*)alloc((size_t)BSZ * DM * 4);
    float* encpart= (float*)alloc((size_t)BSZ * 8 * DM * 4);
    const size_t NP = (size_t)128 * VB;
    float* pm = (float*)alloc(NP * 4);
    float* ps = (float*)alloc(NP * 4);
    float* pv = (float*)alloc(NP * 4 * 4);
    int*   pi = (int*)alloc(NP * 4 * 4);
    int* tokb[2] = {tokb0, tokb1};
    float* scb[2] = {scb0, scb1};

    // encoder context
    ctx_partial_kernel<<<dim3(BSZ, 8), 256, 0, stream>>>(src, embed, wenc, encpart);
    ctx_reduce_kernel<<<BSZ, 512, 0, stream>>>(encpart, ctx);

    // step 0 (all 128 h rows defined; rows 32..127 mirror sentences)
    hidden_kernel<<<dim3(32, 2), 256, 0, stream>>>(embed, wdec, bdec, ctx, ptok, h, 1);
    gemm_topk<<<VB, 256, 0, stream>>>(h, embed, pm, ps, pv, pi, 1, 0);
    reduce_init<<<BSZ, 64, 0, stream>>>(pm, ps, pv, pi, tokb[0], scb[0],
                                        ptok, pscore, bfin);

    // steps 1..48
    for (int s = 1; s <= TGT; s++) {
        hidden_kernel<<<dim3(32, 2), 256, 0, stream>>>(embed, wdec, bdec, ctx, ptok, h, 0);
        gemm_topk<<<VB, 256, 0, stream>>>(h, embed, pm, ps, pv, pi, 0, (s == TGT) ? 1 : 0);
        int cur = (s - 1) & 1, nxt = s & 1;
        reduce_beam<<<BSZ, 256, 0, stream>>>(s, pm, ps, pv, pi,
                                             tokb[cur], tokb[nxt], scb[cur], scb[nxt],
                                             ptok, pscore, bfin);
    }

    // final parity: step 48 wrote buffer 0
    finalize_kernel<<<50, 256, 0, stream>>>(tokb[0], scb[0], bfin,
                                            (float*)d_out);
}